// Round 5
// baseline (312.023 us; speedup 1.0000x reference)
//
#include <hip/hip_runtime.h>

#define N_NODES 50000
#define N_EDGES 800000
#define IN_F    128
#define OUT_F   64
#define N_HEADS 4
#define NEG_SLOPE 0.2f
#define EPS 1e-12f
#define SB 49   // scan blocks: 49 * 1024 = 50176 >= N_NODES

// bf16 helpers (RNE)
__device__ __forceinline__ unsigned short f2bf(float f) {
    unsigned int u = __float_as_uint(f);
    u += 0x7FFFu + ((u >> 16) & 1u);
    return (unsigned short)(u >> 16);
}
__device__ __forceinline__ float bf2f(unsigned short u) {
    return __uint_as_float((unsigned int)u << 16);
}

// ---------------------------------------------------------------------------
// K1: h = x @ W (h stored bf16), fused el = h@a_l, er = h@a_r.
// 4 threads per node; thread owns 16 contiguous output features.
// W read through L1 (4-line broadcast loads, 16 lanes/address). No LDS.
// ---------------------------------------------------------------------------
__global__ __launch_bounds__(256) void k_h_el_er(
    const float* __restrict__ x, const float* __restrict__ W,
    const float* __restrict__ a_l, const float* __restrict__ a_r,
    unsigned short* __restrict__ h_bf,
    float* __restrict__ el, float* __restrict__ er)
{
    const int tid   = blockIdx.x * 256 + threadIdx.x;
    const int node  = tid >> 2;
    const int fpart = tid & 3;
    const int f0    = fpart * 16;
    if (node >= N_NODES) return;

    const float* xrow = x + (size_t)node * IN_F;

    float acc[16];
    #pragma unroll
    for (int i = 0; i < 16; ++i) acc[i] = 0.f;

    #pragma unroll
    for (int kb = 0; kb < IN_F; kb += 4) {
        const float4 xv = *(const float4*)(xrow + kb);
        const float xa[4] = {xv.x, xv.y, xv.z, xv.w};
        #pragma unroll
        for (int kk = 0; kk < 4; ++kk) {
            const float xk = xa[kk];
            const float4* Wv = (const float4*)(W + (size_t)(kb + kk) * OUT_F + f0);
            #pragma unroll
            for (int i = 0; i < 4; ++i) {
                const float4 wv = Wv[i];
                acc[4 * i + 0] += xk * wv.x;
                acc[4 * i + 1] += xk * wv.y;
                acc[4 * i + 2] += xk * wv.z;
                acc[4 * i + 3] += xk * wv.w;
            }
        }
    }

    // store h row chunk as bf16 (16 values = 2 x uint4)
    {
        unsigned int pk[8];
        #pragma unroll
        for (int i = 0; i < 8; ++i)
            pk[i] = (unsigned int)f2bf(acc[2 * i]) |
                    ((unsigned int)f2bf(acc[2 * i + 1]) << 16);
        unsigned int* dst = (unsigned int*)(h_bf + (size_t)node * OUT_F + f0);
        *(uint4*)(dst)     = make_uint4(pk[0], pk[1], pk[2], pk[3]);
        *(uint4*)(dst + 4) = make_uint4(pk[4], pk[5], pk[6], pk[7]);
    }

    // partial el/er over this thread's 16 features
    float4 pl = make_float4(0.f, 0.f, 0.f, 0.f);
    float4 pr = make_float4(0.f, 0.f, 0.f, 0.f);
    #pragma unroll
    for (int j = 0; j < 16; ++j) {
        const float4 al = *(const float4*)(a_l + (size_t)(f0 + j) * N_HEADS);
        const float4 ar = *(const float4*)(a_r + (size_t)(f0 + j) * N_HEADS);
        const float v = acc[j];
        pl.x += v * al.x; pl.y += v * al.y; pl.z += v * al.z; pl.w += v * al.w;
        pr.x += v * ar.x; pr.y += v * ar.y; pr.z += v * ar.z; pr.w += v * ar.w;
    }
    // reduce across the 4 fparts (lanes differ in bits 0..1)
    #pragma unroll
    for (int off = 1; off < 4; off <<= 1) {
        pl.x += __shfl_xor(pl.x, off); pl.y += __shfl_xor(pl.y, off);
        pl.z += __shfl_xor(pl.z, off); pl.w += __shfl_xor(pl.w, off);
        pr.x += __shfl_xor(pr.x, off); pr.y += __shfl_xor(pr.y, off);
        pr.z += __shfl_xor(pr.z, off); pr.w += __shfl_xor(pr.w, off);
    }
    if (fpart == 0) {
        *(float4*)(el + (size_t)node * N_HEADS) = pl;
        *(float4*)(er + (size_t)node * N_HEADS) = pr;
    }
}

// ---------------------------------------------------------------------------
// K2: per-row in-degree count
// ---------------------------------------------------------------------------
__global__ __launch_bounds__(256) void k_count(
    const int* __restrict__ row, int* __restrict__ deg)
{
    int e = blockIdx.x * 256 + threadIdx.x;
    if (e >= N_EDGES) return;
    atomicAdd(&deg[row[e]], 1);
}

// ---------------------------------------------------------------------------
// K3a: per-block exclusive scan (1024 elems/block), emits block totals
// ---------------------------------------------------------------------------
__global__ __launch_bounds__(256) void k_scan_local(
    const int* __restrict__ deg, int* __restrict__ rowptr,
    int* __restrict__ blocksum)
{
    __shared__ int wsum[4];
    const int t = threadIdx.x;
    const int base = blockIdx.x * 1024 + t * 4;

    int4 d = make_int4(0, 0, 0, 0);
    if (base + 3 < N_NODES) d = *(const int4*)(deg + base);
    else {
        if (base + 0 < N_NODES) d.x = deg[base + 0];
        if (base + 1 < N_NODES) d.y = deg[base + 1];
        if (base + 2 < N_NODES) d.z = deg[base + 2];
        if (base + 3 < N_NODES) d.w = deg[base + 3];
    }
    const int tsum = d.x + d.y + d.z + d.w;

    const int lane = t & 63, wave = t >> 6;
    int inc = tsum;
    #pragma unroll
    for (int off = 1; off < 64; off <<= 1) {
        int v = __shfl_up(inc, off);
        if (lane >= off) inc += v;
    }
    if (lane == 63) wsum[wave] = inc;
    __syncthreads();

    int woff = 0;
    #pragma unroll
    for (int w = 0; w < 4; ++w) woff += (w < wave) ? wsum[w] : 0;

    const int ex = woff + inc - tsum;
    int4 o;
    o.x = ex; o.y = ex + d.x; o.z = o.y + d.y; o.w = o.z + d.z;
    if (base + 3 < N_NODES) *(int4*)(rowptr + base) = o;
    else {
        if (base + 0 < N_NODES) rowptr[base + 0] = o.x;
        if (base + 1 < N_NODES) rowptr[base + 1] = o.y;
        if (base + 2 < N_NODES) rowptr[base + 2] = o.z;
        if (base + 3 < N_NODES) rowptr[base + 3] = o.w;
    }
    if (t == 0) blocksum[blockIdx.x] = wsum[0] + wsum[1] + wsum[2] + wsum[3];
}

// ---------------------------------------------------------------------------
// K3b: add preceding-block offsets; block SB-1 writes rowptr[N_NODES]
// ---------------------------------------------------------------------------
__global__ __launch_bounds__(256) void k_scan_add(
    const int* __restrict__ blocksum, int* __restrict__ rowptr)
{
    const int bb = blockIdx.x;
    int off = 0;
    for (int i = 0; i < bb; ++i) off += blocksum[i];

    const int t = threadIdx.x;
    if (bb == SB - 1 && t == 0) rowptr[N_NODES] = off + blocksum[SB - 1];
    if (off == 0) return;

    const int base = bb * 1024 + t * 4;
    if (base + 3 < N_NODES) {
        int4 v = *(int4*)(rowptr + base);
        v.x += off; v.y += off; v.z += off; v.w += off;
        *(int4*)(rowptr + base) = v;
    } else {
        if (base + 0 < N_NODES) rowptr[base + 0] += off;
        if (base + 1 < N_NODES) rowptr[base + 1] += off;
        if (base + 2 < N_NODES) rowptr[base + 2] += off;
        if (base + 3 < N_NODES) rowptr[base + 3] += off;
    }
}

// ---------------------------------------------------------------------------
// K4: scatter edges into CSR slots; optionally precompute exp weights
// ---------------------------------------------------------------------------
template <bool WITH_W>
__global__ __launch_bounds__(256) void k_fill(
    const int* __restrict__ row, const int* __restrict__ col,
    const float* __restrict__ el, const float* __restrict__ er,
    const int* __restrict__ rowptr, int* __restrict__ fill,
    int* __restrict__ csr_col, float4* __restrict__ csr_w)
{
    int e = blockIdx.x * 256 + threadIdx.x;
    if (e >= N_EDGES) return;
    int r = row[e], c = col[e];
    int pos = rowptr[r] + atomicAdd(&fill[r], 1);
    csr_col[pos] = c;
    if (WITH_W) {
        float4 elv = *reinterpret_cast<const float4*>(el + r * 4);
        float4 erv = *reinterpret_cast<const float4*>(er + c * 4);
        float s0 = elv.x + erv.x, s1 = elv.y + erv.y;
        float s2 = elv.z + erv.z, s3 = elv.w + erv.w;
        s0 = s0 > 0.f ? s0 : NEG_SLOPE * s0;
        s1 = s1 > 0.f ? s1 : NEG_SLOPE * s1;
        s2 = s2 > 0.f ? s2 : NEG_SLOPE * s2;
        s3 = s3 > 0.f ? s3 : NEG_SLOPE * s3;
        csr_w[pos] = make_float4(expf(s0), expf(s1), expf(s2), expf(s3));
    }
}

// ---------------------------------------------------------------------------
// K5: gather — one wave per destination node, no atomics. h is bf16.
// ---------------------------------------------------------------------------
template <bool WITH_W>
__global__ __launch_bounds__(256) void k_gather(
    const int* __restrict__ rowptr, const int* __restrict__ csr_col,
    const float4* __restrict__ csr_w,
    const float* __restrict__ el, const float* __restrict__ er,
    const unsigned short* __restrict__ h_bf, const float* __restrict__ b,
    float* __restrict__ out)
{
    int n = blockIdx.x * 4 + (threadIdx.x >> 6);
    if (n >= N_NODES) return;
    const int lane = threadIdx.x & 63;

    const int s0 = rowptr[n], s1 = rowptr[n + 1];

    float a0 = 0.f, a1 = 0.f, a2 = 0.f, a3 = 0.f;
    float d0 = 0.f, d1 = 0.f, d2 = 0.f, d3 = 0.f;

    float4 elv;
    if (!WITH_W) elv = *reinterpret_cast<const float4*>(el + n * 4);

    int j = s0;
    int c_nx = 0;
    float hv_nx = 0.f;
    float4 w_nx = make_float4(0.f, 0.f, 0.f, 0.f);
    if (j < s1) {
        c_nx = csr_col[j];
        if (WITH_W) w_nx = csr_w[j];
        hv_nx = bf2f(h_bf[(size_t)c_nx * OUT_F + lane]);
    }
    while (j < s1) {
        const int c = c_nx;
        const float hv = hv_nx;
        float4 w = w_nx;
        ++j;
        if (j < s1) {
            c_nx = csr_col[j];
            if (WITH_W) w_nx = csr_w[j];
            hv_nx = bf2f(h_bf[(size_t)c_nx * OUT_F + lane]);
        }
        if (!WITH_W) {
            float4 erv = *reinterpret_cast<const float4*>(er + c * 4);
            float s0f = elv.x + erv.x, s1f = elv.y + erv.y;
            float s2f = elv.z + erv.z, s3f = elv.w + erv.w;
            s0f = s0f > 0.f ? s0f : NEG_SLOPE * s0f;
            s1f = s1f > 0.f ? s1f : NEG_SLOPE * s1f;
            s2f = s2f > 0.f ? s2f : NEG_SLOPE * s2f;
            s3f = s3f > 0.f ? s3f : NEG_SLOPE * s3f;
            w = make_float4(expf(s0f), expf(s1f), expf(s2f), expf(s3f));
        }
        d0 += w.x; d1 += w.y; d2 += w.z; d3 += w.w;
        a0 += w.x * hv; a1 += w.y * hv; a2 += w.z * hv; a3 += w.w * hv;
    }

    const float bias = b[lane];
    float* orow = out + (size_t)n * (N_HEADS * OUT_F);
    orow[0 * 64 + lane] = a0 / fmaxf(d0, EPS) + bias;
    orow[1 * 64 + lane] = a1 / fmaxf(d1, EPS) + bias;
    orow[2 * 64 + lane] = a2 / fmaxf(d2, EPS) + bias;
    orow[3 * 64 + lane] = a3 / fmaxf(d3, EPS) + bias;
}

extern "C" void kernel_launch(void* const* d_in, const int* in_sizes, int n_in,
                              void* d_out, int out_size, void* d_ws, size_t ws_size,
                              hipStream_t stream)
{
    const float* x   = (const float*)d_in[0];
    const int*   ei  = (const int*)d_in[1];
    const float* W   = (const float*)d_in[2];
    const float* a_l = (const float*)d_in[3];
    const float* a_r = (const float*)d_in[4];
    const float* b   = (const float*)d_in[5];
    float* out = (float*)d_out;

    char* ws = (char*)d_ws;
    unsigned short* h_bf = (unsigned short*)(ws);      //  6,400,000 B
    float*  el       = (float*) (ws +  6400000);       //    800,000 B
    float*  er       = (float*) (ws +  7200000);       //    800,000 B
    int*    deg      = (int*)   (ws +  8000000);       //    200,000 B
    int*    fill     = (int*)   (ws +  8200000);       //    200,000 B
    int*    rowptr   = (int*)   (ws +  8400000);       //    200,016 B
    int*    blocksum = (int*)   (ws +  8600016);       //        256 B
    int*    csr_col  = (int*)   (ws +  8600272);       //  3,200,000 B
    float4* csr_w    = (float4*)(ws + 11800272);       // 12,800,000 B
    const size_t NEED_W = 24600272;

    const int* row = ei;
    const int* col = ei + N_EDGES;

    hipMemsetAsync(deg, 0, 400000, stream);  // deg + fill contiguous

    k_h_el_er   <<<(N_NODES * 4 + 255) / 256, 256, 0, stream>>>(x, W, a_l, a_r, h_bf, el, er);
    k_count     <<<(N_EDGES + 255) / 256, 256, 0, stream>>>(row, deg);
    k_scan_local<<<SB, 256, 0, stream>>>(deg, rowptr, blocksum);
    k_scan_add  <<<SB, 256, 0, stream>>>(blocksum, rowptr);
    if (ws_size >= NEED_W) {
        k_fill<true>   <<<(N_EDGES + 255) / 256, 256, 0, stream>>>(row, col, el, er, rowptr, fill, csr_col, csr_w);
        k_gather<true> <<<N_NODES / 4, 256, 0, stream>>>(rowptr, csr_col, csr_w, el, er, h_bf, b, out);
    } else {
        k_fill<false>  <<<(N_EDGES + 255) / 256, 256, 0, stream>>>(row, col, el, er, rowptr, fill, csr_col, csr_w);
        k_gather<false><<<N_NODES / 4, 256, 0, stream>>>(rowptr, csr_col, csr_w, el, er, h_bf, b, out);
    }
}

// Round 6
// 227.574 us; speedup vs baseline: 1.3711x; 1.3711x over previous
//
#include <hip/hip_runtime.h>

#define N_NODES 50000
#define N_EDGES 800000
#define IN_F    128
#define OUT_F   64
#define N_HEADS 4
#define NEG_SLOPE 0.2f
#define EPS 1e-12f
#define SB 49   // scan blocks: 49 * 1024 = 50176 >= N_NODES

typedef __attribute__((ext_vector_type(8))) short bf16x8;
typedef __attribute__((ext_vector_type(4))) float f32x4;

// bf16 helpers (RNE)
__device__ __forceinline__ unsigned short f2bf(float f) {
    unsigned int u = __float_as_uint(f);
    u += 0x7FFFu + ((u >> 16) & 1u);
    return (unsigned short)(u >> 16);
}
__device__ __forceinline__ float bf2f(unsigned short u) {
    return __uint_as_float((unsigned int)u << 16);
}

// ---------------------------------------------------------------------------
// K0: Wt[c][k] = bf16(W[k][c])  (transposed so B-frag k's are contiguous)
// ---------------------------------------------------------------------------
__global__ __launch_bounds__(256) void k_prep_w(
    const float* __restrict__ W, unsigned short* __restrict__ Wt)
{
    int i = blockIdx.x * 256 + threadIdx.x;   // over Wt index, 4 blocks
    for (; i < OUT_F * IN_F; i += 4 * 256) {
        int c = i >> 7, k = i & 127;
        Wt[i] = f2bf(W[k * OUT_F + c]);
    }
}

// ---------------------------------------------------------------------------
// K1: h = x @ W via MFMA bf16; fused el = h@a_l, er = h@a_r (f32 epilogue).
// Block = 256 thr = 4 waves; block computes 64 nodes x 64 feats.
// LDS tiles bf16 [64][128], XOR-swizzled (byte ^= (row&7)<<4) for b128 reads.
// Wave w: nodes w*16..+15; A-frag lane l: row l&15, k = (l>>4)*8 contiguous.
// C/D: col = l&15, row = (l>>4)*4 + reg  [verified mapping].
// ---------------------------------------------------------------------------
__global__ __launch_bounds__(256) void k_h_el_er(
    const float* __restrict__ x, const unsigned short* __restrict__ Wt,
    const float* __restrict__ a_l, const float* __restrict__ a_r,
    unsigned short* __restrict__ h_bf,
    float* __restrict__ el, float* __restrict__ er)
{
    __shared__ unsigned short xs[64 * 128];   // 16 KB, swizzled
    __shared__ unsigned short wsh[64 * 128];  // 16 KB, swizzled
    const int tid = threadIdx.x;
    const int node0 = blockIdx.x * 64;

    // stage Wt (16 KB): 1024 uint4, 4 per thread
    {
        const uint4* src = (const uint4*)Wt;
        #pragma unroll
        for (int j = 0; j < 4; ++j) {
            int idx = tid + 256 * j;          // uint4 index; byte = idx*16
            int row = idx >> 4;               // 16 uint4 per 256-B row
            int cb  = (idx & 15) << 4;
            uint4 v = src[idx];
            *(uint4*)((char*)wsh + row * 256 + (cb ^ ((row & 7) << 4))) = v;
        }
    }
    // stage x rows node0..node0+63 (f32 -> bf16): thread t: row t>>2, 32 floats
    {
        const int row = tid >> 2;
        const int c0  = (tid & 3) * 32;
        const int node = node0 + row;
        unsigned int pk[16];
        if (node < N_NODES) {
            const float* src = x + (size_t)node * IN_F + c0;
            #pragma unroll
            for (int i = 0; i < 8; ++i) {
                float4 v = *(const float4*)(src + 4 * i);
                pk[2 * i + 0] = (unsigned)f2bf(v.x) | ((unsigned)f2bf(v.y) << 16);
                pk[2 * i + 1] = (unsigned)f2bf(v.z) | ((unsigned)f2bf(v.w) << 16);
            }
        } else {
            #pragma unroll
            for (int i = 0; i < 16; ++i) pk[i] = 0;
        }
        #pragma unroll
        for (int q = 0; q < 4; ++q) {
            int cb = c0 * 2 + q * 16;
            *(uint4*)((char*)xs + row * 256 + (cb ^ ((row & 7) << 4))) =
                make_uint4(pk[4 * q], pk[4 * q + 1], pk[4 * q + 2], pk[4 * q + 3]);
        }
    }
    __syncthreads();

    const int w  = tid >> 6, l = tid & 63;
    const int lr = l & 15, lg = l >> 4;
    const int arow = w * 16 + lr;

    bf16x8 afr[4];
    #pragma unroll
    for (int t = 0; t < 4; ++t) {
        int cb = t * 64 + lg * 16;
        afr[t] = *(const bf16x8*)((char*)xs + arow * 256 + (cb ^ ((arow & 7) << 4)));
    }

    const f32x4 zero = {0.f, 0.f, 0.f, 0.f};
    f32x4 acc[4] = {zero, zero, zero, zero};
    #pragma unroll
    for (int nt = 0; nt < 4; ++nt) {
        const int brow = nt * 16 + lr;
        #pragma unroll
        for (int t = 0; t < 4; ++t) {
            int cb = t * 64 + lg * 16;
            bf16x8 bfr = *(const bf16x8*)((char*)wsh + brow * 256 + (cb ^ ((brow & 7) << 4)));
            acc[nt] = __builtin_amdgcn_mfma_f32_16x16x32_bf16(afr[t], bfr, acc[nt], 0, 0, 0);
        }
    }

    // h stores: lane l holds rows lg*4+r, cols nt*16+lr
    #pragma unroll
    for (int r = 0; r < 4; ++r) {
        const int node = node0 + w * 16 + lg * 4 + r;
        if (node < N_NODES) {
            #pragma unroll
            for (int nt = 0; nt < 4; ++nt)
                h_bf[(size_t)node * OUT_F + nt * 16 + lr] = f2bf(acc[nt][r]);
        }
    }

    // el/er epilogue from f32 accumulators
    float4 al4[4], ar4[4];
    #pragma unroll
    for (int nt = 0; nt < 4; ++nt) {
        al4[nt] = *(const float4*)(a_l + (size_t)(nt * 16 + lr) * N_HEADS);
        ar4[nt] = *(const float4*)(a_r + (size_t)(nt * 16 + lr) * N_HEADS);
    }
    #pragma unroll
    for (int r = 0; r < 4; ++r) {
        float4 pl = make_float4(0.f, 0.f, 0.f, 0.f);
        float4 pr = make_float4(0.f, 0.f, 0.f, 0.f);
        #pragma unroll
        for (int nt = 0; nt < 4; ++nt) {
            const float v = acc[nt][r];
            pl.x += v * al4[nt].x; pl.y += v * al4[nt].y;
            pl.z += v * al4[nt].z; pl.w += v * al4[nt].w;
            pr.x += v * ar4[nt].x; pr.y += v * ar4[nt].y;
            pr.z += v * ar4[nt].z; pr.w += v * ar4[nt].w;
        }
        #pragma unroll
        for (int off = 1; off < 16; off <<= 1) {
            pl.x += __shfl_xor(pl.x, off); pl.y += __shfl_xor(pl.y, off);
            pl.z += __shfl_xor(pl.z, off); pl.w += __shfl_xor(pl.w, off);
            pr.x += __shfl_xor(pr.x, off); pr.y += __shfl_xor(pr.y, off);
            pr.z += __shfl_xor(pr.z, off); pr.w += __shfl_xor(pr.w, off);
        }
        const int node = node0 + w * 16 + lg * 4 + r;
        if (lr == 0 && node < N_NODES) {
            *(float4*)(el + (size_t)node * N_HEADS) = pl;
            *(float4*)(er + (size_t)node * N_HEADS) = pr;
        }
    }
}

// ---------------------------------------------------------------------------
// K2: per-row in-degree count
// ---------------------------------------------------------------------------
__global__ __launch_bounds__(256) void k_count(
    const int* __restrict__ row, int* __restrict__ deg)
{
    int e = blockIdx.x * 256 + threadIdx.x;
    if (e >= N_EDGES) return;
    atomicAdd(&deg[row[e]], 1);
}

// ---------------------------------------------------------------------------
// K3a: per-block exclusive scan (1024 elems/block), emits block totals
// ---------------------------------------------------------------------------
__global__ __launch_bounds__(256) void k_scan_local(
    const int* __restrict__ deg, int* __restrict__ rowptr,
    int* __restrict__ blocksum)
{
    __shared__ int wsum[4];
    const int t = threadIdx.x;
    const int base = blockIdx.x * 1024 + t * 4;

    int4 d = make_int4(0, 0, 0, 0);
    if (base + 3 < N_NODES) d = *(const int4*)(deg + base);
    else {
        if (base + 0 < N_NODES) d.x = deg[base + 0];
        if (base + 1 < N_NODES) d.y = deg[base + 1];
        if (base + 2 < N_NODES) d.z = deg[base + 2];
        if (base + 3 < N_NODES) d.w = deg[base + 3];
    }
    const int tsum = d.x + d.y + d.z + d.w;

    const int lane = t & 63, wave = t >> 6;
    int inc = tsum;
    #pragma unroll
    for (int off = 1; off < 64; off <<= 1) {
        int v = __shfl_up(inc, off);
        if (lane >= off) inc += v;
    }
    if (lane == 63) wsum[wave] = inc;
    __syncthreads();

    int woff = 0;
    #pragma unroll
    for (int w = 0; w < 4; ++w) woff += (w < wave) ? wsum[w] : 0;

    const int ex = woff + inc - tsum;
    int4 o;
    o.x = ex; o.y = ex + d.x; o.z = o.y + d.y; o.w = o.z + d.z;
    if (base + 3 < N_NODES) *(int4*)(rowptr + base) = o;
    else {
        if (base + 0 < N_NODES) rowptr[base + 0] = o.x;
        if (base + 1 < N_NODES) rowptr[base + 1] = o.y;
        if (base + 2 < N_NODES) rowptr[base + 2] = o.z;
        if (base + 3 < N_NODES) rowptr[base + 3] = o.w;
    }
    if (t == 0) blocksum[blockIdx.x] = wsum[0] + wsum[1] + wsum[2] + wsum[3];
}

// ---------------------------------------------------------------------------
// K3b: add preceding-block offsets; block SB-1 writes rowptr[N_NODES]
// ---------------------------------------------------------------------------
__global__ __launch_bounds__(256) void k_scan_add(
    const int* __restrict__ blocksum, int* __restrict__ rowptr)
{
    const int bb = blockIdx.x;
    int off = 0;
    for (int i = 0; i < bb; ++i) off += blocksum[i];

    const int t = threadIdx.x;
    if (bb == SB - 1 && t == 0) rowptr[N_NODES] = off + blocksum[SB - 1];
    if (off == 0) return;

    const int base = bb * 1024 + t * 4;
    if (base + 3 < N_NODES) {
        int4 v = *(int4*)(rowptr + base);
        v.x += off; v.y += off; v.z += off; v.w += off;
        *(int4*)(rowptr + base) = v;
    } else {
        if (base + 0 < N_NODES) rowptr[base + 0] += off;
        if (base + 1 < N_NODES) rowptr[base + 1] += off;
        if (base + 2 < N_NODES) rowptr[base + 2] += off;
        if (base + 3 < N_NODES) rowptr[base + 3] += off;
    }
}

// ---------------------------------------------------------------------------
// K4: scatter edges into CSR slots (col only; weights computed in gather)
// ---------------------------------------------------------------------------
__global__ __launch_bounds__(256) void k_fill(
    const int* __restrict__ row, const int* __restrict__ col,
    const int* __restrict__ rowptr, int* __restrict__ fill,
    int* __restrict__ csr_col)
{
    int e = blockIdx.x * 256 + threadIdx.x;
    if (e >= N_EDGES) return;
    int r = row[e];
    int pos = rowptr[r] + atomicAdd(&fill[r], 1);
    csr_col[pos] = col[e];
}

// ---------------------------------------------------------------------------
// K5: gather — one wave per destination node, no atomics. h is bf16;
// attention weight recomputed per edge (er is L2-resident).
// ---------------------------------------------------------------------------
__global__ __launch_bounds__(256) void k_gather(
    const int* __restrict__ rowptr, const int* __restrict__ csr_col,
    const float* __restrict__ el, const float* __restrict__ er,
    const unsigned short* __restrict__ h_bf, const float* __restrict__ b,
    float* __restrict__ out)
{
    int n = blockIdx.x * 4 + (threadIdx.x >> 6);
    if (n >= N_NODES) return;
    const int lane = threadIdx.x & 63;

    const int s0 = rowptr[n], s1 = rowptr[n + 1];

    float a0 = 0.f, a1 = 0.f, a2 = 0.f, a3 = 0.f;
    float d0 = 0.f, d1 = 0.f, d2 = 0.f, d3 = 0.f;

    const float4 elv = *reinterpret_cast<const float4*>(el + (size_t)n * 4);

    int j = s0;
    int c_nx = 0;
    float hv_nx = 0.f;
    float4 erv_nx = make_float4(0.f, 0.f, 0.f, 0.f);
    if (j < s1) {
        c_nx = csr_col[j];
        hv_nx = bf2f(h_bf[(size_t)c_nx * OUT_F + lane]);
        erv_nx = *reinterpret_cast<const float4*>(er + (size_t)c_nx * 4);
    }
    while (j < s1) {
        const float hv = hv_nx;
        const float4 erv = erv_nx;
        ++j;
        if (j < s1) {
            c_nx = csr_col[j];
            hv_nx = bf2f(h_bf[(size_t)c_nx * OUT_F + lane]);
            erv_nx = *reinterpret_cast<const float4*>(er + (size_t)c_nx * 4);
        }
        float s0f = elv.x + erv.x, s1f = elv.y + erv.y;
        float s2f = elv.z + erv.z, s3f = elv.w + erv.w;
        s0f = s0f > 0.f ? s0f : NEG_SLOPE * s0f;
        s1f = s1f > 0.f ? s1f : NEG_SLOPE * s1f;
        s2f = s2f > 0.f ? s2f : NEG_SLOPE * s2f;
        s3f = s3f > 0.f ? s3f : NEG_SLOPE * s3f;
        const float w0 = expf(s0f), w1 = expf(s1f);
        const float w2 = expf(s2f), w3 = expf(s3f);
        d0 += w0; d1 += w1; d2 += w2; d3 += w3;
        a0 += w0 * hv; a1 += w1 * hv; a2 += w2 * hv; a3 += w3 * hv;
    }

    const float bias = b[lane];
    float* orow = out + (size_t)n * (N_HEADS * OUT_F);
    orow[0 * 64 + lane] = a0 / fmaxf(d0, EPS) + bias;
    orow[1 * 64 + lane] = a1 / fmaxf(d1, EPS) + bias;
    orow[2 * 64 + lane] = a2 / fmaxf(d2, EPS) + bias;
    orow[3 * 64 + lane] = a3 / fmaxf(d3, EPS) + bias;
}

extern "C" void kernel_launch(void* const* d_in, const int* in_sizes, int n_in,
                              void* d_out, int out_size, void* d_ws, size_t ws_size,
                              hipStream_t stream)
{
    const float* x   = (const float*)d_in[0];
    const int*   ei  = (const int*)d_in[1];
    const float* W   = (const float*)d_in[2];
    const float* a_l = (const float*)d_in[3];
    const float* a_r = (const float*)d_in[4];
    const float* b   = (const float*)d_in[5];
    float* out = (float*)d_out;

    char* ws = (char*)d_ws;
    unsigned short* h_bf = (unsigned short*)(ws);      //  6,400,000 B
    float*  el       = (float*) (ws +  6400000);       //    800,000 B
    float*  er       = (float*) (ws +  7200000);       //    800,000 B
    int*    deg      = (int*)   (ws +  8000000);       //    200,000 B
    int*    fill     = (int*)   (ws +  8200000);       //    200,000 B
    int*    rowptr   = (int*)   (ws +  8400000);       //    200,016 B
    int*    blocksum = (int*)   (ws +  8600016);       //        256 B
    int*    csr_col  = (int*)   (ws +  8600272);       //  3,200,000 B
    unsigned short* Wt = (unsigned short*)(ws + 11800272); // 16,384 B

    const int* row = ei;
    const int* col = ei + N_EDGES;

    hipMemsetAsync(deg, 0, 400000, stream);  // deg + fill contiguous

    k_prep_w    <<<4, 256, 0, stream>>>(W, Wt);
    k_count     <<<(N_EDGES + 255) / 256, 256, 0, stream>>>(row, deg);
    k_h_el_er   <<<(N_NODES + 63) / 64, 256, 0, stream>>>(x, Wt, a_l, a_r, h_bf, el, er);
    k_scan_local<<<SB, 256, 0, stream>>>(deg, rowptr, blocksum);
    k_scan_add  <<<SB, 256, 0, stream>>>(blocksum, rowptr);
    k_fill      <<<(N_EDGES + 255) / 256, 256, 0, stream>>>(row, col, rowptr, fill, csr_col);
    k_gather    <<<N_NODES / 4, 256, 0, stream>>>(rowptr, csr_col, el, er, h_bf, b, out);
}

// Round 7
// 148.302 us; speedup vs baseline: 2.1040x; 1.5345x over previous
//
#include <hip/hip_runtime.h>

#define N_NODES 50000
#define N_EDGES 800000
#define IN_F    128
#define OUT_F   64
#define N_HEADS 4
#define NEG_SLOPE 0.2f
#define EPS 1e-12f
#define SB 49   // scan blocks: 49 * 1024 = 50176 >= N_NODES

typedef __attribute__((ext_vector_type(8))) short bf16x8;
typedef __attribute__((ext_vector_type(4))) float f32x4;

// bf16 helpers (RNE)
__device__ __forceinline__ unsigned short f2bf(float f) {
    unsigned int u = __float_as_uint(f);
    u += 0x7FFFu + ((u >> 16) & 1u);
    return (unsigned short)(u >> 16);
}

// ---------------------------------------------------------------------------
// K0: Wt[c][k] = bf16(W[k][c])  (transposed so B-frag k's are contiguous)
// ---------------------------------------------------------------------------
__global__ __launch_bounds__(256) void k_prep_w(
    const float* __restrict__ W, unsigned short* __restrict__ Wt)
{
    int i = blockIdx.x * 256 + threadIdx.x;
    for (; i < OUT_F * IN_F; i += 4 * 256) {
        int c = i >> 7, k = i & 127;
        Wt[i] = f2bf(W[k * OUT_F + c]);
    }
}

// ---------------------------------------------------------------------------
// K1: h = x @ W via MFMA bf16; fused el = h@a_l, er = h@a_r (f32 epilogue).
// Block = 256 thr = 4 waves; block computes 64 nodes x 64 feats.
// LDS tiles bf16 [64][128], XOR-swizzled (byte ^= (row&7)<<4) for b128 reads.
// C/D: col = l&15, row = (l>>4)*4 + reg  [verified mapping].
// ---------------------------------------------------------------------------
__global__ __launch_bounds__(256) void k_h_el_er(
    const float* __restrict__ x, const unsigned short* __restrict__ Wt,
    const float* __restrict__ a_l, const float* __restrict__ a_r,
    unsigned short* __restrict__ h_bf,
    float* __restrict__ el, float* __restrict__ er)
{
    __shared__ unsigned short xs[64 * 128];   // 16 KB, swizzled
    __shared__ unsigned short wsh[64 * 128];  // 16 KB, swizzled
    const int tid = threadIdx.x;
    const int node0 = blockIdx.x * 64;

    {
        const uint4* src = (const uint4*)Wt;
        #pragma unroll
        for (int j = 0; j < 4; ++j) {
            int idx = tid + 256 * j;
            int row = idx >> 4;
            int cb  = (idx & 15) << 4;
            uint4 v = src[idx];
            *(uint4*)((char*)wsh + row * 256 + (cb ^ ((row & 7) << 4))) = v;
        }
    }
    {
        const int row = tid >> 2;
        const int c0  = (tid & 3) * 32;
        const int node = node0 + row;
        unsigned int pk[16];
        if (node < N_NODES) {
            const float* src = x + (size_t)node * IN_F + c0;
            #pragma unroll
            for (int i = 0; i < 8; ++i) {
                float4 v = *(const float4*)(src + 4 * i);
                pk[2 * i + 0] = (unsigned)f2bf(v.x) | ((unsigned)f2bf(v.y) << 16);
                pk[2 * i + 1] = (unsigned)f2bf(v.z) | ((unsigned)f2bf(v.w) << 16);
            }
        } else {
            #pragma unroll
            for (int i = 0; i < 16; ++i) pk[i] = 0;
        }
        #pragma unroll
        for (int q = 0; q < 4; ++q) {
            int cb = c0 * 2 + q * 16;
            *(uint4*)((char*)xs + row * 256 + (cb ^ ((row & 7) << 4))) =
                make_uint4(pk[4 * q], pk[4 * q + 1], pk[4 * q + 2], pk[4 * q + 3]);
        }
    }
    __syncthreads();

    const int w  = tid >> 6, l = tid & 63;
    const int lr = l & 15, lg = l >> 4;
    const int arow = w * 16 + lr;

    bf16x8 afr[4];
    #pragma unroll
    for (int t = 0; t < 4; ++t) {
        int cb = t * 64 + lg * 16;
        afr[t] = *(const bf16x8*)((char*)xs + arow * 256 + (cb ^ ((arow & 7) << 4)));
    }

    const f32x4 zero = {0.f, 0.f, 0.f, 0.f};
    f32x4 acc[4] = {zero, zero, zero, zero};
    #pragma unroll
    for (int nt = 0; nt < 4; ++nt) {
        const int brow = nt * 16 + lr;
        #pragma unroll
        for (int t = 0; t < 4; ++t) {
            int cb = t * 64 + lg * 16;
            bf16x8 bfr = *(const bf16x8*)((char*)wsh + brow * 256 + (cb ^ ((brow & 7) << 4)));
            acc[nt] = __builtin_amdgcn_mfma_f32_16x16x32_bf16(afr[t], bfr, acc[nt], 0, 0, 0);
        }
    }

    #pragma unroll
    for (int r = 0; r < 4; ++r) {
        const int node = node0 + w * 16 + lg * 4 + r;
        if (node < N_NODES) {
            #pragma unroll
            for (int nt = 0; nt < 4; ++nt)
                h_bf[(size_t)node * OUT_F + nt * 16 + lr] = f2bf(acc[nt][r]);
        }
    }

    float4 al4[4], ar4[4];
    #pragma unroll
    for (int nt = 0; nt < 4; ++nt) {
        al4[nt] = *(const float4*)(a_l + (size_t)(nt * 16 + lr) * N_HEADS);
        ar4[nt] = *(const float4*)(a_r + (size_t)(nt * 16 + lr) * N_HEADS);
    }
    #pragma unroll
    for (int r = 0; r < 4; ++r) {
        float4 pl = make_float4(0.f, 0.f, 0.f, 0.f);
        float4 pr = make_float4(0.f, 0.f, 0.f, 0.f);
        #pragma unroll
        for (int nt = 0; nt < 4; ++nt) {
            const float v = acc[nt][r];
            pl.x += v * al4[nt].x; pl.y += v * al4[nt].y;
            pl.z += v * al4[nt].z; pl.w += v * al4[nt].w;
            pr.x += v * ar4[nt].x; pr.y += v * ar4[nt].y;
            pr.z += v * ar4[nt].z; pr.w += v * ar4[nt].w;
        }
        #pragma unroll
        for (int off = 1; off < 16; off <<= 1) {
            pl.x += __shfl_xor(pl.x, off); pl.y += __shfl_xor(pl.y, off);
            pl.z += __shfl_xor(pl.z, off); pl.w += __shfl_xor(pl.w, off);
            pr.x += __shfl_xor(pr.x, off); pr.y += __shfl_xor(pr.y, off);
            pr.z += __shfl_xor(pr.z, off); pr.w += __shfl_xor(pr.w, off);
        }
        const int node = node0 + w * 16 + lg * 4 + r;
        if (lr == 0 && node < N_NODES) {
            *(float4*)(el + (size_t)node * N_HEADS) = pl;
            *(float4*)(er + (size_t)node * N_HEADS) = pr;
        }
    }
}

// ---------------------------------------------------------------------------
// K2: per-row in-degree count
// ---------------------------------------------------------------------------
__global__ __launch_bounds__(256) void k_count(
    const int* __restrict__ row, int* __restrict__ deg)
{
    int e = blockIdx.x * 256 + threadIdx.x;
    if (e >= N_EDGES) return;
    atomicAdd(&deg[row[e]], 1);
}

// ---------------------------------------------------------------------------
// K3a: per-block exclusive scan (1024 elems/block), emits block totals
// ---------------------------------------------------------------------------
__global__ __launch_bounds__(256) void k_scan_local(
    const int* __restrict__ deg, int* __restrict__ rowptr,
    int* __restrict__ blocksum)
{
    __shared__ int wsum[4];
    const int t = threadIdx.x;
    const int base = blockIdx.x * 1024 + t * 4;

    int4 d = make_int4(0, 0, 0, 0);
    if (base + 3 < N_NODES) d = *(const int4*)(deg + base);
    else {
        if (base + 0 < N_NODES) d.x = deg[base + 0];
        if (base + 1 < N_NODES) d.y = deg[base + 1];
        if (base + 2 < N_NODES) d.z = deg[base + 2];
        if (base + 3 < N_NODES) d.w = deg[base + 3];
    }
    const int tsum = d.x + d.y + d.z + d.w;

    const int lane = t & 63, wave = t >> 6;
    int inc = tsum;
    #pragma unroll
    for (int off = 1; off < 64; off <<= 1) {
        int v = __shfl_up(inc, off);
        if (lane >= off) inc += v;
    }
    if (lane == 63) wsum[wave] = inc;
    __syncthreads();

    int woff = 0;
    #pragma unroll
    for (int w = 0; w < 4; ++w) woff += (w < wave) ? wsum[w] : 0;

    const int ex = woff + inc - tsum;
    int4 o;
    o.x = ex; o.y = ex + d.x; o.z = o.y + d.y; o.w = o.z + d.z;
    if (base + 3 < N_NODES) *(int4*)(rowptr + base) = o;
    else {
        if (base + 0 < N_NODES) rowptr[base + 0] = o.x;
        if (base + 1 < N_NODES) rowptr[base + 1] = o.y;
        if (base + 2 < N_NODES) rowptr[base + 2] = o.z;
        if (base + 3 < N_NODES) rowptr[base + 3] = o.w;
    }
    if (t == 0) blocksum[blockIdx.x] = wsum[0] + wsum[1] + wsum[2] + wsum[3];
}

// ---------------------------------------------------------------------------
// K3b: add preceding-block offsets; block SB-1 writes rowptr[N_NODES]
// ---------------------------------------------------------------------------
__global__ __launch_bounds__(256) void k_scan_add(
    const int* __restrict__ blocksum, int* __restrict__ rowptr)
{
    const int bb = blockIdx.x;
    int off = 0;
    for (int i = 0; i < bb; ++i) off += blocksum[i];

    const int t = threadIdx.x;
    if (bb == SB - 1 && t == 0) rowptr[N_NODES] = off + blocksum[SB - 1];
    if (off == 0) return;

    const int base = bb * 1024 + t * 4;
    if (base + 3 < N_NODES) {
        int4 v = *(int4*)(rowptr + base);
        v.x += off; v.y += off; v.z += off; v.w += off;
        *(int4*)(rowptr + base) = v;
    } else {
        if (base + 0 < N_NODES) rowptr[base + 0] += off;
        if (base + 1 < N_NODES) rowptr[base + 1] += off;
        if (base + 2 < N_NODES) rowptr[base + 2] += off;
        if (base + 3 < N_NODES) rowptr[base + 3] += off;
    }
}

// ---------------------------------------------------------------------------
// K4: scatter edges into CSR slots; precompute exp weights (fast exp, 1
// thread per edge -- no redundant lane work).
// ---------------------------------------------------------------------------
template <bool WITH_W>
__global__ __launch_bounds__(256) void k_fill(
    const int* __restrict__ row, const int* __restrict__ col,
    const float* __restrict__ el, const float* __restrict__ er,
    const int* __restrict__ rowptr, int* __restrict__ fill,
    int* __restrict__ csr_col, float4* __restrict__ csr_w)
{
    int e = blockIdx.x * 256 + threadIdx.x;
    if (e >= N_EDGES) return;
    int r = row[e], c = col[e];
    int pos = rowptr[r] + atomicAdd(&fill[r], 1);
    csr_col[pos] = c;
    if (WITH_W) {
        float4 elv = *reinterpret_cast<const float4*>(el + (size_t)r * 4);
        float4 erv = *reinterpret_cast<const float4*>(er + (size_t)c * 4);
        float s0 = elv.x + erv.x, s1 = elv.y + erv.y;
        float s2 = elv.z + erv.z, s3 = elv.w + erv.w;
        s0 = s0 > 0.f ? s0 : NEG_SLOPE * s0;
        s1 = s1 > 0.f ? s1 : NEG_SLOPE * s1;
        s2 = s2 > 0.f ? s2 : NEG_SLOPE * s2;
        s3 = s3 > 0.f ? s3 : NEG_SLOPE * s3;
        csr_w[pos] = make_float4(__expf(s0), __expf(s1), __expf(s2), __expf(s3));
    }
}

// ---------------------------------------------------------------------------
// K5: gather — one wave per node; 4 x 16-lane groups process 4 edges per
// iteration. Lane (g, fq) accumulates acc[head][4 feats fq*4..+3] partials
// for group g's edges; one cross-group shfl_xor reduce per node; group g
// writes head g's output quad (coalesced 1 KB per node).
// ---------------------------------------------------------------------------
template <bool WITH_W>
__global__ __launch_bounds__(256) void k_gather(
    const int* __restrict__ rowptr, const int* __restrict__ csr_col,
    const float4* __restrict__ csr_w,
    const float* __restrict__ el, const float* __restrict__ er,
    const unsigned short* __restrict__ h_bf, const float* __restrict__ b,
    float* __restrict__ out)
{
    int n = blockIdx.x * 4 + (threadIdx.x >> 6);
    if (n >= N_NODES) return;
    const int lane = threadIdx.x & 63;
    const int g    = lane >> 4;    // group == output head at the end
    const int fq   = lane & 15;    // feature quad: feats fq*4 .. +3

    const int s0 = rowptr[n], s1 = rowptr[n + 1];
    const int deg = s1 - s0;

    float acc[4][4];
    #pragma unroll
    for (int hd = 0; hd < 4; ++hd)
        #pragma unroll
        for (int f = 0; f < 4; ++f) acc[hd][f] = 0.f;
    float den[4] = {0.f, 0.f, 0.f, 0.f};

    float4 elv;
    if (!WITH_W) elv = *reinterpret_cast<const float4*>(el + (size_t)n * 4);

    const int nit = (deg + 3) >> 2;
    for (int it = 0; it < nit; ++it) {
        const int j = s0 + it * 4 + g;
        const bool valid = j < s1;
        const int jc = valid ? j : (s1 - 1);
        const int c = csr_col[jc];              // uniform within group
        float4 w;
        if (WITH_W) {
            w = csr_w[jc];                      // uniform within group
        } else {
            float4 erv = *reinterpret_cast<const float4*>(er + (size_t)c * 4);
            float t0 = elv.x + erv.x, t1 = elv.y + erv.y;
            float t2 = elv.z + erv.z, t3 = elv.w + erv.w;
            t0 = t0 > 0.f ? t0 : NEG_SLOPE * t0;
            t1 = t1 > 0.f ? t1 : NEG_SLOPE * t1;
            t2 = t2 > 0.f ? t2 : NEG_SLOPE * t2;
            t3 = t3 > 0.f ? t3 : NEG_SLOPE * t3;
            w = make_float4(__expf(t0), __expf(t1), __expf(t2), __expf(t3));
        }
        if (!valid) w = make_float4(0.f, 0.f, 0.f, 0.f);

        const uint2 hraw = *(const uint2*)(h_bf + (size_t)c * OUT_F + fq * 4);
        const float h0 = __uint_as_float(hraw.x << 16);
        const float h1 = __uint_as_float(hraw.x & 0xFFFF0000u);
        const float h2 = __uint_as_float(hraw.y << 16);
        const float h3 = __uint_as_float(hraw.y & 0xFFFF0000u);

        den[0] += w.x; den[1] += w.y; den[2] += w.z; den[3] += w.w;
        acc[0][0] += w.x * h0; acc[0][1] += w.x * h1; acc[0][2] += w.x * h2; acc[0][3] += w.x * h3;
        acc[1][0] += w.y * h0; acc[1][1] += w.y * h1; acc[1][2] += w.y * h2; acc[1][3] += w.y * h3;
        acc[2][0] += w.z * h0; acc[2][1] += w.z * h1; acc[2][2] += w.z * h2; acc[2][3] += w.z * h3;
        acc[3][0] += w.w * h0; acc[3][1] += w.w * h1; acc[3][2] += w.w * h2; acc[3][3] += w.w * h3;
    }

    // reduce partials across the 4 groups (lanes xor 16, 32)
    #pragma unroll
    for (int hd = 0; hd < 4; ++hd) {
        float v = den[hd];
        v += __shfl_xor(v, 16); v += __shfl_xor(v, 32);
        den[hd] = v;
        #pragma unroll
        for (int f = 0; f < 4; ++f) {
            float u = acc[hd][f];
            u += __shfl_xor(u, 16); u += __shfl_xor(u, 32);
            acc[hd][f] = u;
        }
    }

    // select this group's head (compile-time array idx, runtime cndmask sel)
    const float dg = g == 0 ? den[0] : g == 1 ? den[1] : g == 2 ? den[2] : den[3];
    const float inv = 1.f / fmaxf(dg, EPS);
    float4 o;
    o.x = (g == 0 ? acc[0][0] : g == 1 ? acc[1][0] : g == 2 ? acc[2][0] : acc[3][0]);
    o.y = (g == 0 ? acc[0][1] : g == 1 ? acc[1][1] : g == 2 ? acc[2][1] : acc[3][1]);
    o.z = (g == 0 ? acc[0][2] : g == 1 ? acc[1][2] : g == 2 ? acc[2][2] : acc[3][2]);
    o.w = (g == 0 ? acc[0][3] : g == 1 ? acc[1][3] : g == 2 ? acc[2][3] : acc[3][3]);

    const float4 bias = *(const float4*)(b + fq * 4);
    o.x = o.x * inv + bias.x;
    o.y = o.y * inv + bias.y;
    o.z = o.z * inv + bias.z;
    o.w = o.w * inv + bias.w;
    *(float4*)(out + (size_t)n * (N_HEADS * OUT_F) + g * 64 + fq * 4) = o;
}

extern "C" void kernel_launch(void* const* d_in, const int* in_sizes, int n_in,
                              void* d_out, int out_size, void* d_ws, size_t ws_size,
                              hipStream_t stream)
{
    const float* x   = (const float*)d_in[0];
    const int*   ei  = (const int*)d_in[1];
    const float* W   = (const float*)d_in[2];
    const float* a_l = (const float*)d_in[3];
    const float* a_r = (const float*)d_in[4];
    const float* b   = (const float*)d_in[5];
    float* out = (float*)d_out;

    char* ws = (char*)d_ws;
    unsigned short* h_bf = (unsigned short*)(ws);      //  6,400,000 B
    float*  el       = (float*) (ws +  6400000);       //    800,000 B
    float*  er       = (float*) (ws +  7200000);       //    800,000 B
    int*    deg      = (int*)   (ws +  8000000);       //    200,000 B
    int*    fill     = (int*)   (ws +  8200000);       //    200,000 B
    int*    rowptr   = (int*)   (ws +  8400000);       //    200,016 B
    int*    blocksum = (int*)   (ws +  8600016);       //        256 B
    int*    csr_col  = (int*)   (ws +  8600272);       //  3,200,000 B
    unsigned short* Wt = (unsigned short*)(ws + 11800272); // 16,384 B
    float4* csr_w    = (float4*)(ws + 11816656);       // 12,800,000 B
    const size_t NEED_W = 24616656;

    const int* row = ei;
    const int* col = ei + N_EDGES;

    hipMemsetAsync(deg, 0, 400000, stream);  // deg + fill contiguous

    k_prep_w    <<<4, 256, 0, stream>>>(W, Wt);
    k_count     <<<(N_EDGES + 255) / 256, 256, 0, stream>>>(row, deg);
    k_h_el_er   <<<(N_NODES + 63) / 64, 256, 0, stream>>>(x, Wt, a_l, a_r, h_bf, el, er);
    k_scan_local<<<SB, 256, 0, stream>>>(deg, rowptr, blocksum);
    k_scan_add  <<<SB, 256, 0, stream>>>(blocksum, rowptr);
    if (ws_size >= NEED_W) {
        k_fill<true>   <<<(N_EDGES + 255) / 256, 256, 0, stream>>>(row, col, el, er, rowptr, fill, csr_col, csr_w);
        k_gather<true> <<<N_NODES / 4, 256, 0, stream>>>(rowptr, csr_col, csr_w, el, er, h_bf, b, out);
    } else {
        k_fill<false>  <<<(N_EDGES + 255) / 256, 256, 0, stream>>>(row, col, el, er, rowptr, fill, csr_col, csr_w);
        k_gather<false><<<N_NODES / 4, 256, 0, stream>>>(rowptr, csr_col, csr_w, el, er, h_bf, b, out);
    }
}

// Round 8
// 135.646 us; speedup vs baseline: 2.3003x; 1.0933x over previous
//
#include <hip/hip_runtime.h>

#define N_NODES 50000
#define N_EDGES 800000
#define IN_F    128
#define OUT_F   64
#define N_HEADS 4
#define NEG_SLOPE 0.2f
#define EPS 1e-12f
#define SB 49   // scan blocks: 49 * 1024 = 50176 >= N_NODES

typedef __attribute__((ext_vector_type(8))) short bf16x8;
typedef __attribute__((ext_vector_type(4))) float f32x4;

// bf16 helpers (RNE)
__device__ __forceinline__ unsigned short f2bf(float f) {
    unsigned int u = __float_as_uint(f);
    u += 0x7FFFu + ((u >> 16) & 1u);
    return (unsigned short)(u >> 16);
}

// ---------------------------------------------------------------------------
// K0: Wt[c][k] = bf16(W[k][c])  (transposed so B-frag k's are contiguous)
// ---------------------------------------------------------------------------
__global__ __launch_bounds__(256) void k_prep_w(
    const float* __restrict__ W, unsigned short* __restrict__ Wt)
{
    int i = blockIdx.x * 256 + threadIdx.x;
    for (; i < OUT_F * IN_F; i += 4 * 256) {
        int c = i >> 7, k = i & 127;
        Wt[i] = f2bf(W[k * OUT_F + c]);
    }
}

// ---------------------------------------------------------------------------
// K1: h = x @ W via MFMA bf16; fused el = h@a_l, er = h@a_r (f32 epilogue).
// Block = 256 thr = 4 waves; block computes 64 nodes x 64 feats.
// LDS tiles bf16 [64][128], XOR-swizzled (byte ^= (row&7)<<4) for b128 reads.
// C/D: col = l&15, row = (l>>4)*4 + reg  [verified mapping].
// ---------------------------------------------------------------------------
__global__ __launch_bounds__(256) void k_h_el_er(
    const float* __restrict__ x, const unsigned short* __restrict__ Wt,
    const float* __restrict__ a_l, const float* __restrict__ a_r,
    unsigned short* __restrict__ h_bf,
    float* __restrict__ el, float* __restrict__ er)
{
    __shared__ unsigned short xs[64 * 128];   // 16 KB, swizzled
    __shared__ unsigned short wsh[64 * 128];  // 16 KB, swizzled
    const int tid = threadIdx.x;
    const int node0 = blockIdx.x * 64;

    {
        const uint4* src = (const uint4*)Wt;
        #pragma unroll
        for (int j = 0; j < 4; ++j) {
            int idx = tid + 256 * j;
            int row = idx >> 4;
            int cb  = (idx & 15) << 4;
            uint4 v = src[idx];
            *(uint4*)((char*)wsh + row * 256 + (cb ^ ((row & 7) << 4))) = v;
        }
    }
    {
        const int row = tid >> 2;
        const int c0  = (tid & 3) * 32;
        const int node = node0 + row;
        unsigned int pk[16];
        if (node < N_NODES) {
            const float* src = x + (size_t)node * IN_F + c0;
            #pragma unroll
            for (int i = 0; i < 8; ++i) {
                float4 v = *(const float4*)(src + 4 * i);
                pk[2 * i + 0] = (unsigned)f2bf(v.x) | ((unsigned)f2bf(v.y) << 16);
                pk[2 * i + 1] = (unsigned)f2bf(v.z) | ((unsigned)f2bf(v.w) << 16);
            }
        } else {
            #pragma unroll
            for (int i = 0; i < 16; ++i) pk[i] = 0;
        }
        #pragma unroll
        for (int q = 0; q < 4; ++q) {
            int cb = c0 * 2 + q * 16;
            *(uint4*)((char*)xs + row * 256 + (cb ^ ((row & 7) << 4))) =
                make_uint4(pk[4 * q], pk[4 * q + 1], pk[4 * q + 2], pk[4 * q + 3]);
        }
    }
    __syncthreads();

    const int w  = tid >> 6, l = tid & 63;
    const int lr = l & 15, lg = l >> 4;
    const int arow = w * 16 + lr;

    bf16x8 afr[4];
    #pragma unroll
    for (int t = 0; t < 4; ++t) {
        int cb = t * 64 + lg * 16;
        afr[t] = *(const bf16x8*)((char*)xs + arow * 256 + (cb ^ ((arow & 7) << 4)));
    }

    const f32x4 zero = {0.f, 0.f, 0.f, 0.f};
    f32x4 acc[4] = {zero, zero, zero, zero};
    #pragma unroll
    for (int nt = 0; nt < 4; ++nt) {
        const int brow = nt * 16 + lr;
        #pragma unroll
        for (int t = 0; t < 4; ++t) {
            int cb = t * 64 + lg * 16;
            bf16x8 bfr = *(const bf16x8*)((char*)wsh + brow * 256 + (cb ^ ((brow & 7) << 4)));
            acc[nt] = __builtin_amdgcn_mfma_f32_16x16x32_bf16(afr[t], bfr, acc[nt], 0, 0, 0);
        }
    }

    #pragma unroll
    for (int r = 0; r < 4; ++r) {
        const int node = node0 + w * 16 + lg * 4 + r;
        if (node < N_NODES) {
            #pragma unroll
            for (int nt = 0; nt < 4; ++nt)
                h_bf[(size_t)node * OUT_F + nt * 16 + lr] = f2bf(acc[nt][r]);
        }
    }

    float4 al4[4], ar4[4];
    #pragma unroll
    for (int nt = 0; nt < 4; ++nt) {
        al4[nt] = *(const float4*)(a_l + (size_t)(nt * 16 + lr) * N_HEADS);
        ar4[nt] = *(const float4*)(a_r + (size_t)(nt * 16 + lr) * N_HEADS);
    }
    #pragma unroll
    for (int r = 0; r < 4; ++r) {
        float4 pl = make_float4(0.f, 0.f, 0.f, 0.f);
        float4 pr = make_float4(0.f, 0.f, 0.f, 0.f);
        #pragma unroll
        for (int nt = 0; nt < 4; ++nt) {
            const float v = acc[nt][r];
            pl.x += v * al4[nt].x; pl.y += v * al4[nt].y;
            pl.z += v * al4[nt].z; pl.w += v * al4[nt].w;
            pr.x += v * ar4[nt].x; pr.y += v * ar4[nt].y;
            pr.z += v * ar4[nt].z; pr.w += v * ar4[nt].w;
        }
        #pragma unroll
        for (int off = 1; off < 16; off <<= 1) {
            pl.x += __shfl_xor(pl.x, off); pl.y += __shfl_xor(pl.y, off);
            pl.z += __shfl_xor(pl.z, off); pl.w += __shfl_xor(pl.w, off);
            pr.x += __shfl_xor(pr.x, off); pr.y += __shfl_xor(pr.y, off);
            pr.z += __shfl_xor(pr.z, off); pr.w += __shfl_xor(pr.w, off);
        }
        const int node = node0 + w * 16 + lg * 4 + r;
        if (lr == 0 && node < N_NODES) {
            *(float4*)(el + (size_t)node * N_HEADS) = pl;
            *(float4*)(er + (size_t)node * N_HEADS) = pr;
        }
    }
}

// ---------------------------------------------------------------------------
// K2: in-degree count + per-edge rank within its row (one atomic pass)
// ---------------------------------------------------------------------------
__global__ __launch_bounds__(256) void k_count_rank(
    const int* __restrict__ row, int* __restrict__ deg, int* __restrict__ rank)
{
    int e = blockIdx.x * 256 + threadIdx.x;
    if (e >= N_EDGES) return;
    rank[e] = atomicAdd(&deg[row[e]], 1);
}

// ---------------------------------------------------------------------------
// K3a: per-block exclusive scan (1024 elems/block), emits block totals
// ---------------------------------------------------------------------------
__global__ __launch_bounds__(256) void k_scan_local(
    const int* __restrict__ deg, int* __restrict__ rowptr,
    int* __restrict__ blocksum)
{
    __shared__ int wsum[4];
    const int t = threadIdx.x;
    const int base = blockIdx.x * 1024 + t * 4;

    int4 d = make_int4(0, 0, 0, 0);
    if (base + 3 < N_NODES) d = *(const int4*)(deg + base);
    else {
        if (base + 0 < N_NODES) d.x = deg[base + 0];
        if (base + 1 < N_NODES) d.y = deg[base + 1];
        if (base + 2 < N_NODES) d.z = deg[base + 2];
        if (base + 3 < N_NODES) d.w = deg[base + 3];
    }
    const int tsum = d.x + d.y + d.z + d.w;

    const int lane = t & 63, wave = t >> 6;
    int inc = tsum;
    #pragma unroll
    for (int off = 1; off < 64; off <<= 1) {
        int v = __shfl_up(inc, off);
        if (lane >= off) inc += v;
    }
    if (lane == 63) wsum[wave] = inc;
    __syncthreads();

    int woff = 0;
    #pragma unroll
    for (int w = 0; w < 4; ++w) woff += (w < wave) ? wsum[w] : 0;

    const int ex = woff + inc - tsum;
    int4 o;
    o.x = ex; o.y = ex + d.x; o.z = o.y + d.y; o.w = o.z + d.z;
    if (base + 3 < N_NODES) *(int4*)(rowptr + base) = o;
    else {
        if (base + 0 < N_NODES) rowptr[base + 0] = o.x;
        if (base + 1 < N_NODES) rowptr[base + 1] = o.y;
        if (base + 2 < N_NODES) rowptr[base + 2] = o.z;
        if (base + 3 < N_NODES) rowptr[base + 3] = o.w;
    }
    if (t == 0) blocksum[blockIdx.x] = wsum[0] + wsum[1] + wsum[2] + wsum[3];
}

// ---------------------------------------------------------------------------
// K3b: add preceding-block offsets; block SB-1 writes rowptr[N_NODES]
// ---------------------------------------------------------------------------
__global__ __launch_bounds__(256) void k_scan_add(
    const int* __restrict__ blocksum, int* __restrict__ rowptr)
{
    const int bb = blockIdx.x;
    int off = 0;
    for (int i = 0; i < bb; ++i) off += blocksum[i];

    const int t = threadIdx.x;
    if (bb == SB - 1 && t == 0) rowptr[N_NODES] = off + blocksum[SB - 1];
    if (off == 0) return;

    const int base = bb * 1024 + t * 4;
    if (base + 3 < N_NODES) {
        int4 v = *(int4*)(rowptr + base);
        v.x += off; v.y += off; v.z += off; v.w += off;
        *(int4*)(rowptr + base) = v;
    } else {
        if (base + 0 < N_NODES) rowptr[base + 0] += off;
        if (base + 1 < N_NODES) rowptr[base + 1] += off;
        if (base + 2 < N_NODES) rowptr[base + 2] += off;
        if (base + 3 < N_NODES) rowptr[base + 3] += off;
    }
}

// ---------------------------------------------------------------------------
// K4: atomic-free CSR scatter: pos = rowptr[row] + rank (nt store)
// ---------------------------------------------------------------------------
__global__ __launch_bounds__(256) void k_fill(
    const int* __restrict__ row, const int* __restrict__ col,
    const int* __restrict__ rank, const int* __restrict__ rowptr,
    int* __restrict__ csr_col)
{
    int e = blockIdx.x * 256 + threadIdx.x;
    if (e >= N_EDGES) return;
    int pos = rowptr[row[e]] + rank[e];
    __builtin_nontemporal_store(col[e], &csr_col[pos]);
}

// ---------------------------------------------------------------------------
// K5: gather — one wave per node; 4 x 16-lane groups process 4 edges per
// iteration. Weights recomputed in-loop (cheap: ~6 wave-ops/edge, __expf).
// One cross-group shfl_xor reduce per node; group g writes head g's quad.
// ---------------------------------------------------------------------------
__global__ __launch_bounds__(256) void k_gather(
    const int* __restrict__ rowptr, const int* __restrict__ csr_col,
    const float* __restrict__ el, const float* __restrict__ er,
    const unsigned short* __restrict__ h_bf, const float* __restrict__ b,
    float* __restrict__ out)
{
    int n = blockIdx.x * 4 + (threadIdx.x >> 6);
    if (n >= N_NODES) return;
    const int lane = threadIdx.x & 63;
    const int g    = lane >> 4;    // group == output head at the end
    const int fq   = lane & 15;    // feature quad: feats fq*4 .. +3

    const int s0 = rowptr[n], s1 = rowptr[n + 1];
    const int deg = s1 - s0;

    float acc[4][4];
    #pragma unroll
    for (int hd = 0; hd < 4; ++hd)
        #pragma unroll
        for (int f = 0; f < 4; ++f) acc[hd][f] = 0.f;
    float den[4] = {0.f, 0.f, 0.f, 0.f};

    const float4 elv = *reinterpret_cast<const float4*>(el + (size_t)n * 4);

    const int nit = (deg + 3) >> 2;
    for (int it = 0; it < nit; ++it) {
        const int j = s0 + it * 4 + g;
        const bool valid = j < s1;
        const int jc = valid ? j : (s1 - 1);
        const int c = csr_col[jc];              // uniform within group

        float4 erv = *reinterpret_cast<const float4*>(er + (size_t)c * 4);
        float t0 = elv.x + erv.x, t1 = elv.y + erv.y;
        float t2 = elv.z + erv.z, t3 = elv.w + erv.w;
        t0 = t0 > 0.f ? t0 : NEG_SLOPE * t0;
        t1 = t1 > 0.f ? t1 : NEG_SLOPE * t1;
        t2 = t2 > 0.f ? t2 : NEG_SLOPE * t2;
        t3 = t3 > 0.f ? t3 : NEG_SLOPE * t3;
        float4 w = make_float4(__expf(t0), __expf(t1), __expf(t2), __expf(t3));
        if (!valid) w = make_float4(0.f, 0.f, 0.f, 0.f);

        const uint2 hraw = *(const uint2*)(h_bf + (size_t)c * OUT_F + fq * 4);
        const float h0 = __uint_as_float(hraw.x << 16);
        const float h1 = __uint_as_float(hraw.x & 0xFFFF0000u);
        const float h2 = __uint_as_float(hraw.y << 16);
        const float h3 = __uint_as_float(hraw.y & 0xFFFF0000u);

        den[0] += w.x; den[1] += w.y; den[2] += w.z; den[3] += w.w;
        acc[0][0] += w.x * h0; acc[0][1] += w.x * h1; acc[0][2] += w.x * h2; acc[0][3] += w.x * h3;
        acc[1][0] += w.y * h0; acc[1][1] += w.y * h1; acc[1][2] += w.y * h2; acc[1][3] += w.y * h3;
        acc[2][0] += w.z * h0; acc[2][1] += w.z * h1; acc[2][2] += w.z * h2; acc[2][3] += w.z * h3;
        acc[3][0] += w.w * h0; acc[3][1] += w.w * h1; acc[3][2] += w.w * h2; acc[3][3] += w.w * h3;
    }

    // reduce partials across the 4 groups (lanes xor 16, 32)
    #pragma unroll
    for (int hd = 0; hd < 4; ++hd) {
        float v = den[hd];
        v += __shfl_xor(v, 16); v += __shfl_xor(v, 32);
        den[hd] = v;
        #pragma unroll
        for (int f = 0; f < 4; ++f) {
            float u = acc[hd][f];
            u += __shfl_xor(u, 16); u += __shfl_xor(u, 32);
            acc[hd][f] = u;
        }
    }

    const float dg = g == 0 ? den[0] : g == 1 ? den[1] : g == 2 ? den[2] : den[3];
    const float inv = 1.f / fmaxf(dg, EPS);
    float4 o;
    o.x = (g == 0 ? acc[0][0] : g == 1 ? acc[1][0] : g == 2 ? acc[2][0] : acc[3][0]);
    o.y = (g == 0 ? acc[0][1] : g == 1 ? acc[1][1] : g == 2 ? acc[2][1] : acc[3][1]);
    o.z = (g == 0 ? acc[0][2] : g == 1 ? acc[1][2] : g == 2 ? acc[2][2] : acc[3][2]);
    o.w = (g == 0 ? acc[0][3] : g == 1 ? acc[1][3] : g == 2 ? acc[2][3] : acc[3][3]);

    const float4 bias = *(const float4*)(b + fq * 4);
    o.x = o.x * inv + bias.x;
    o.y = o.y * inv + bias.y;
    o.z = o.z * inv + bias.z;
    o.w = o.w * inv + bias.w;
    *(float4*)(out + (size_t)n * (N_HEADS * OUT_F) + g * 64 + fq * 4) = o;
}

extern "C" void kernel_launch(void* const* d_in, const int* in_sizes, int n_in,
                              void* d_out, int out_size, void* d_ws, size_t ws_size,
                              hipStream_t stream)
{
    const float* x   = (const float*)d_in[0];
    const int*   ei  = (const int*)d_in[1];
    const float* W   = (const float*)d_in[2];
    const float* a_l = (const float*)d_in[3];
    const float* a_r = (const float*)d_in[4];
    const float* b   = (const float*)d_in[5];
    float* out = (float*)d_out;

    char* ws = (char*)d_ws;
    unsigned short* h_bf = (unsigned short*)(ws);      //  6,400,000 B
    float*  el       = (float*) (ws +  6400000);       //    800,000 B
    float*  er       = (float*) (ws +  7200000);       //    800,000 B
    int*    deg      = (int*)   (ws +  8000000);       //    200,000 B
    int*    rank     = (int*)   (ws +  8200000);       //  3,200,000 B
    int*    rowptr   = (int*)   (ws + 11400000);       //    200,016 B
    int*    blocksum = (int*)   (ws + 11600016);       //        256 B
    int*    csr_col  = (int*)   (ws + 11600272);       //  3,200,000 B
    unsigned short* Wt = (unsigned short*)(ws + 14800272); // 16,384 B

    const int* row = ei;
    const int* col = ei + N_EDGES;

    hipMemsetAsync(deg, 0, 200000, stream);

    k_prep_w    <<<4, 256, 0, stream>>>(W, Wt);
    k_count_rank<<<(N_EDGES + 255) / 256, 256, 0, stream>>>(row, deg, rank);
    k_h_el_er   <<<(N_NODES + 63) / 64, 256, 0, stream>>>(x, Wt, a_l, a_r, h_bf, el, er);
    k_scan_local<<<SB, 256, 0, stream>>>(deg, rowptr, blocksum);
    k_scan_add  <<<SB, 256, 0, stream>>>(blocksum, rowptr);
    k_fill      <<<(N_EDGES + 255) / 256, 256, 0, stream>>>(row, col, rank, rowptr, csr_col);
    k_gather    <<<N_NODES / 4, 256, 0, stream>>>(rowptr, csr_col, el, er, h_bf, b, out);
}

// Round 9
// 129.352 us; speedup vs baseline: 2.4122x; 1.0487x over previous
//
#include <hip/hip_runtime.h>

#define N_NODES 50000
#define N_EDGES 800000
#define IN_F    128
#define OUT_F   64
#define N_HEADS 4
#define NEG_SLOPE 0.2f
#define EPS 1e-12f
#define SB 49           // scan blocks: 49 * 1024 = 50176 >= N_NODES
#define EDGE_BLOCKS 3125  // 3125 * 256 = 800000 exactly
#define NODE_BLOCKS 782   // ceil(50000 / 64)

typedef __attribute__((ext_vector_type(8))) short bf16x8;
typedef __attribute__((ext_vector_type(4))) float f32x4;

// bf16 helpers (RNE)
__device__ __forceinline__ unsigned short f2bf(float f) {
    unsigned int u = __float_as_uint(f);
    u += 0x7FFFu + ((u >> 16) & 1u);
    return (unsigned short)(u >> 16);
}

// ---------------------------------------------------------------------------
// K0: blocks 0-3: Wt[c][k] = bf16(W[k][c]); blocks 4-52: zero deg
// ---------------------------------------------------------------------------
__global__ __launch_bounds__(256) void k_init(
    const float* __restrict__ W, unsigned short* __restrict__ Wt,
    int* __restrict__ deg)
{
    const int bb = blockIdx.x;
    const int tid = threadIdx.x;
    if (bb < 4) {
        int i = bb * 256 + tid;
        for (; i < OUT_F * IN_F; i += 4 * 256) {
            int c = i >> 7, k = i & 127;
            Wt[i] = f2bf(W[k * OUT_F + c]);
        }
    } else {
        const int base = (bb - 4) * 1024 + tid * 4;
        if (base + 3 < N_NODES) *(int4*)(deg + base) = make_int4(0, 0, 0, 0);
        else {
            if (base + 0 < N_NODES) deg[base + 0] = 0;
            if (base + 1 < N_NODES) deg[base + 1] = 0;
            if (base + 2 < N_NODES) deg[base + 2] = 0;
            if (base + 3 < N_NODES) deg[base + 3] = 0;
        }
    }
}

// ---------------------------------------------------------------------------
// K1 fused: blocks [0, EDGE_BLOCKS): count+rank (atomic, latency-bound,
// dispatched first); blocks [EDGE_BLOCKS, +NODE_BLOCKS): h = x@W via MFMA
// with fused el/er epilogue (compute-bound, hides the atomic tail).
// LDS tiles bf16 [64][128], XOR-swizzled (byte ^= (row&7)<<4).
// MFMA C/D: col = l&15, row = (l>>4)*4 + reg  [verified mapping].
// ---------------------------------------------------------------------------
__global__ __launch_bounds__(256) void k_fused(
    const float* __restrict__ x, const unsigned short* __restrict__ Wt,
    const float* __restrict__ a_l, const float* __restrict__ a_r,
    const int* __restrict__ row, int* __restrict__ deg, int* __restrict__ rank,
    unsigned short* __restrict__ h_bf,
    float* __restrict__ el, float* __restrict__ er)
{
    __shared__ unsigned short xs[64 * 128];   // 16 KB, swizzled
    __shared__ unsigned short wsh[64 * 128];  // 16 KB, swizzled
    const int tid = threadIdx.x;

    if (blockIdx.x < EDGE_BLOCKS) {
        const int e = blockIdx.x * 256 + tid;
        rank[e] = atomicAdd(&deg[row[e]], 1);
        return;
    }

    const int node0 = (blockIdx.x - EDGE_BLOCKS) * 64;

    {
        const uint4* src = (const uint4*)Wt;
        #pragma unroll
        for (int j = 0; j < 4; ++j) {
            int idx = tid + 256 * j;
            int r = idx >> 4;
            int cb = (idx & 15) << 4;
            uint4 v = src[idx];
            *(uint4*)((char*)wsh + r * 256 + (cb ^ ((r & 7) << 4))) = v;
        }
    }
    {
        const int r = tid >> 2;
        const int c0 = (tid & 3) * 32;
        const int node = node0 + r;
        unsigned int pk[16];
        if (node < N_NODES) {
            const float* src = x + (size_t)node * IN_F + c0;
            #pragma unroll
            for (int i = 0; i < 8; ++i) {
                float4 v = *(const float4*)(src + 4 * i);
                pk[2 * i + 0] = (unsigned)f2bf(v.x) | ((unsigned)f2bf(v.y) << 16);
                pk[2 * i + 1] = (unsigned)f2bf(v.z) | ((unsigned)f2bf(v.w) << 16);
            }
        } else {
            #pragma unroll
            for (int i = 0; i < 16; ++i) pk[i] = 0;
        }
        #pragma unroll
        for (int q = 0; q < 4; ++q) {
            int cb = c0 * 2 + q * 16;
            *(uint4*)((char*)xs + r * 256 + (cb ^ ((r & 7) << 4))) =
                make_uint4(pk[4 * q], pk[4 * q + 1], pk[4 * q + 2], pk[4 * q + 3]);
        }
    }
    __syncthreads();

    const int w  = tid >> 6, l = tid & 63;
    const int lr = l & 15, lg = l >> 4;
    const int arow = w * 16 + lr;

    bf16x8 afr[4];
    #pragma unroll
    for (int t = 0; t < 4; ++t) {
        int cb = t * 64 + lg * 16;
        afr[t] = *(const bf16x8*)((char*)xs + arow * 256 + (cb ^ ((arow & 7) << 4)));
    }

    const f32x4 zero = {0.f, 0.f, 0.f, 0.f};
    f32x4 acc[4] = {zero, zero, zero, zero};
    #pragma unroll
    for (int nt = 0; nt < 4; ++nt) {
        const int brow = nt * 16 + lr;
        #pragma unroll
        for (int t = 0; t < 4; ++t) {
            int cb = t * 64 + lg * 16;
            bf16x8 bfr = *(const bf16x8*)((char*)wsh + brow * 256 + (cb ^ ((brow & 7) << 4)));
            acc[nt] = __builtin_amdgcn_mfma_f32_16x16x32_bf16(afr[t], bfr, acc[nt], 0, 0, 0);
        }
    }

    #pragma unroll
    for (int r = 0; r < 4; ++r) {
        const int node = node0 + w * 16 + lg * 4 + r;
        if (node < N_NODES) {
            #pragma unroll
            for (int nt = 0; nt < 4; ++nt)
                h_bf[(size_t)node * OUT_F + nt * 16 + lr] = f2bf(acc[nt][r]);
        }
    }

    float4 al4[4], ar4[4];
    #pragma unroll
    for (int nt = 0; nt < 4; ++nt) {
        al4[nt] = *(const float4*)(a_l + (size_t)(nt * 16 + lr) * N_HEADS);
        ar4[nt] = *(const float4*)(a_r + (size_t)(nt * 16 + lr) * N_HEADS);
    }
    #pragma unroll
    for (int r = 0; r < 4; ++r) {
        float4 pl = make_float4(0.f, 0.f, 0.f, 0.f);
        float4 pr = make_float4(0.f, 0.f, 0.f, 0.f);
        #pragma unroll
        for (int nt = 0; nt < 4; ++nt) {
            const float v = acc[nt][r];
            pl.x += v * al4[nt].x; pl.y += v * al4[nt].y;
            pl.z += v * al4[nt].z; pl.w += v * al4[nt].w;
            pr.x += v * ar4[nt].x; pr.y += v * ar4[nt].y;
            pr.z += v * ar4[nt].z; pr.w += v * ar4[nt].w;
        }
        #pragma unroll
        for (int off = 1; off < 16; off <<= 1) {
            pl.x += __shfl_xor(pl.x, off); pl.y += __shfl_xor(pl.y, off);
            pl.z += __shfl_xor(pl.z, off); pl.w += __shfl_xor(pl.w, off);
            pr.x += __shfl_xor(pr.x, off); pr.y += __shfl_xor(pr.y, off);
            pr.z += __shfl_xor(pr.z, off); pr.w += __shfl_xor(pr.w, off);
        }
        const int node = node0 + w * 16 + lg * 4 + r;
        if (lr == 0 && node < N_NODES) {
            *(float4*)(el + (size_t)node * N_HEADS) = pl;
            *(float4*)(er + (size_t)node * N_HEADS) = pr;
        }
    }
}

// ---------------------------------------------------------------------------
// K3a: per-block exclusive scan (1024 elems/block), emits block totals
// ---------------------------------------------------------------------------
__global__ __launch_bounds__(256) void k_scan_local(
    const int* __restrict__ deg, int* __restrict__ rowptr,
    int* __restrict__ blocksum)
{
    __shared__ int wsum[4];
    const int t = threadIdx.x;
    const int base = blockIdx.x * 1024 + t * 4;

    int4 d = make_int4(0, 0, 0, 0);
    if (base + 3 < N_NODES) d = *(const int4*)(deg + base);
    else {
        if (base + 0 < N_NODES) d.x = deg[base + 0];
        if (base + 1 < N_NODES) d.y = deg[base + 1];
        if (base + 2 < N_NODES) d.z = deg[base + 2];
        if (base + 3 < N_NODES) d.w = deg[base + 3];
    }
    const int tsum = d.x + d.y + d.z + d.w;

    const int lane = t & 63, wave = t >> 6;
    int inc = tsum;
    #pragma unroll
    for (int off = 1; off < 64; off <<= 1) {
        int v = __shfl_up(inc, off);
        if (lane >= off) inc += v;
    }
    if (lane == 63) wsum[wave] = inc;
    __syncthreads();

    int woff = 0;
    #pragma unroll
    for (int w = 0; w < 4; ++w) woff += (w < wave) ? wsum[w] : 0;

    const int ex = woff + inc - tsum;
    int4 o;
    o.x = ex; o.y = ex + d.x; o.z = o.y + d.y; o.w = o.z + d.z;
    if (base + 3 < N_NODES) *(int4*)(rowptr + base) = o;
    else {
        if (base + 0 < N_NODES) rowptr[base + 0] = o.x;
        if (base + 1 < N_NODES) rowptr[base + 1] = o.y;
        if (base + 2 < N_NODES) rowptr[base + 2] = o.z;
        if (base + 3 < N_NODES) rowptr[base + 3] = o.w;
    }
    if (t == 0) blocksum[blockIdx.x] = wsum[0] + wsum[1] + wsum[2] + wsum[3];
}

// ---------------------------------------------------------------------------
// K3b: add preceding-block offsets; block SB-1 writes rowptr[N_NODES]
// ---------------------------------------------------------------------------
__global__ __launch_bounds__(256) void k_scan_add(
    const int* __restrict__ blocksum, int* __restrict__ rowptr)
{
    const int bb = blockIdx.x;
    int off = 0;
    for (int i = 0; i < bb; ++i) off += blocksum[i];

    const int t = threadIdx.x;
    if (bb == SB - 1 && t == 0) rowptr[N_NODES] = off + blocksum[SB - 1];
    if (off == 0) return;

    const int base = bb * 1024 + t * 4;
    if (base + 3 < N_NODES) {
        int4 v = *(int4*)(rowptr + base);
        v.x += off; v.y += off; v.z += off; v.w += off;
        *(int4*)(rowptr + base) = v;
    } else {
        if (base + 0 < N_NODES) rowptr[base + 0] += off;
        if (base + 1 < N_NODES) rowptr[base + 1] += off;
        if (base + 2 < N_NODES) rowptr[base + 2] += off;
        if (base + 3 < N_NODES) rowptr[base + 3] += off;
    }
}

// ---------------------------------------------------------------------------
// K4: atomic-free CSR scatter: pos = rowptr[row] + rank (nt store)
// ---------------------------------------------------------------------------
__global__ __launch_bounds__(256) void k_fill(
    const int* __restrict__ row, const int* __restrict__ col,
    const int* __restrict__ rank, const int* __restrict__ rowptr,
    int* __restrict__ csr_col)
{
    int e = blockIdx.x * 256 + threadIdx.x;
    if (e >= N_EDGES) return;
    int pos = rowptr[row[e]] + rank[e];
    __builtin_nontemporal_store(col[e], &csr_col[pos]);
}

// ---------------------------------------------------------------------------
// K5: gather — one wave per node; 4 x 16-lane groups, 4 edges/iter, with a
// 1-ahead software pipeline on (csr_col -> er, h). 32-bit element offsets.
// ---------------------------------------------------------------------------
__global__ __launch_bounds__(256) void k_gather(
    const int* __restrict__ rowptr, const int* __restrict__ csr_col,
    const float* __restrict__ el, const float* __restrict__ er,
    const unsigned short* __restrict__ h_bf, const float* __restrict__ b,
    float* __restrict__ out)
{
    int n = blockIdx.x * 4 + (threadIdx.x >> 6);
    if (n >= N_NODES) return;
    const int lane = threadIdx.x & 63;
    const int g    = lane >> 4;    // group == output head at the end
    const int fq   = lane & 15;    // feature quad: feats fq*4 .. +3

    const int s0 = rowptr[n], s1 = rowptr[n + 1];
    const int deg = s1 - s0;
    const int nit = (deg + 3) >> 2;

    float acc[4][4];
    #pragma unroll
    for (int hd = 0; hd < 4; ++hd)
        #pragma unroll
        for (int f = 0; f < 4; ++f) acc[hd][f] = 0.f;
    float den[4] = {0.f, 0.f, 0.f, 0.f};

    const float4 elv = *reinterpret_cast<const float4*>(el + ((unsigned)n << 2));

    bool v_cur = false;
    float4 erv_cur = make_float4(0.f, 0.f, 0.f, 0.f);
    uint2  h_cur = make_uint2(0, 0);
    if (nit > 0) {
        const int j = s0 + g;
        v_cur = j < s1;
        const int jc = v_cur ? j : (s1 - 1);
        const int c = csr_col[jc];
        erv_cur = *reinterpret_cast<const float4*>(er + ((unsigned)c << 2));
        h_cur   = *reinterpret_cast<const uint2*>(h_bf + (((unsigned)c << 6) + (fq << 2)));
    }

    for (int it = 0; it < nit; ++it) {
        bool v_nx = false;
        float4 erv_nx = make_float4(0.f, 0.f, 0.f, 0.f);
        uint2  h_nx = make_uint2(0, 0);
        if (it + 1 < nit) {
            const int j = s0 + (it + 1) * 4 + g;
            v_nx = j < s1;
            const int jc = v_nx ? j : (s1 - 1);
            const int c = csr_col[jc];
            erv_nx = *reinterpret_cast<const float4*>(er + ((unsigned)c << 2));
            h_nx   = *reinterpret_cast<const uint2*>(h_bf + (((unsigned)c << 6) + (fq << 2)));
        }

        float t0 = elv.x + erv_cur.x, t1 = elv.y + erv_cur.y;
        float t2 = elv.z + erv_cur.z, t3 = elv.w + erv_cur.w;
        t0 = t0 > 0.f ? t0 : NEG_SLOPE * t0;
        t1 = t1 > 0.f ? t1 : NEG_SLOPE * t1;
        t2 = t2 > 0.f ? t2 : NEG_SLOPE * t2;
        t3 = t3 > 0.f ? t3 : NEG_SLOPE * t3;
        float4 w = make_float4(__expf(t0), __expf(t1), __expf(t2), __expf(t3));
        if (!v_cur) w = make_float4(0.f, 0.f, 0.f, 0.f);

        const float h0 = __uint_as_float(h_cur.x << 16);
        const float h1 = __uint_as_float(h_cur.x & 0xFFFF0000u);
        const float h2 = __uint_as_float(h_cur.y << 16);
        const float h3 = __uint_as_float(h_cur.y & 0xFFFF0000u);

        den[0] += w.x; den[1] += w.y; den[2] += w.z; den[3] += w.w;
        acc[0][0] += w.x * h0; acc[0][1] += w.x * h1; acc[0][2] += w.x * h2; acc[0][3] += w.x * h3;
        acc[1][0] += w.y * h0; acc[1][1] += w.y * h1; acc[1][2] += w.y * h2; acc[1][3] += w.y * h3;
        acc[2][0] += w.z * h0; acc[2][1] += w.z * h1; acc[2][2] += w.z * h2; acc[2][3] += w.z * h3;
        acc[3][0] += w.w * h0; acc[3][1] += w.w * h1; acc[3][2] += w.w * h2; acc[3][3] += w.w * h3;

        v_cur = v_nx; erv_cur = erv_nx; h_cur = h_nx;
    }

    // reduce partials across the 4 groups (lanes xor 16, 32)
    #pragma unroll
    for (int hd = 0; hd < 4; ++hd) {
        float v = den[hd];
        v += __shfl_xor(v, 16); v += __shfl_xor(v, 32);
        den[hd] = v;
        #pragma unroll
        for (int f = 0; f < 4; ++f) {
            float u = acc[hd][f];
            u += __shfl_xor(u, 16); u += __shfl_xor(u, 32);
            acc[hd][f] = u;
        }
    }

    const float dg = g == 0 ? den[0] : g == 1 ? den[1] : g == 2 ? den[2] : den[3];
    const float inv = 1.f / fmaxf(dg, EPS);
    float4 o;
    o.x = (g == 0 ? acc[0][0] : g == 1 ? acc[1][0] : g == 2 ? acc[2][0] : acc[3][0]);
    o.y = (g == 0 ? acc[0][1] : g == 1 ? acc[1][1] : g == 2 ? acc[2][1] : acc[3][1]);
    o.z = (g == 0 ? acc[0][2] : g == 1 ? acc[1][2] : g == 2 ? acc[2][2] : acc[3][2]);
    o.w = (g == 0 ? acc[0][3] : g == 1 ? acc[1][3] : g == 2 ? acc[2][3] : acc[3][3]);

    const float4 bias = *(const float4*)(b + fq * 4);
    o.x = o.x * inv + bias.x;
    o.y = o.y * inv + bias.y;
    o.z = o.z * inv + bias.z;
    o.w = o.w * inv + bias.w;
    *(float4*)(out + (size_t)n * (N_HEADS * OUT_F) + g * 64 + fq * 4) = o;
}

extern "C" void kernel_launch(void* const* d_in, const int* in_sizes, int n_in,
                              void* d_out, int out_size, void* d_ws, size_t ws_size,
                              hipStream_t stream)
{
    const float* x   = (const float*)d_in[0];
    const int*   ei  = (const int*)d_in[1];
    const float* W   = (const float*)d_in[2];
    const float* a_l = (const float*)d_in[3];
    const float* a_r = (const float*)d_in[4];
    const float* b   = (const float*)d_in[5];
    float* out = (float*)d_out;

    char* ws = (char*)d_ws;
    unsigned short* h_bf = (unsigned short*)(ws);      //  6,400,000 B
    float*  el       = (float*) (ws +  6400000);       //    800,000 B
    float*  er       = (float*) (ws +  7200000);       //    800,000 B
    int*    deg      = (int*)   (ws +  8000000);       //    200,000 B
    int*    rank     = (int*)   (ws +  8200000);       //  3,200,000 B
    int*    rowptr   = (int*)   (ws + 11400000);       //    200,016 B
    int*    blocksum = (int*)   (ws + 11600016);       //        256 B
    int*    csr_col  = (int*)   (ws + 11600272);       //  3,200,000 B
    unsigned short* Wt = (unsigned short*)(ws + 14800272); // 16,384 B

    const int* row = ei;
    const int* col = ei + N_EDGES;

    k_init      <<<53, 256, 0, stream>>>(W, Wt, deg);
    k_fused     <<<EDGE_BLOCKS + NODE_BLOCKS, 256, 0, stream>>>(
                    x, Wt, a_l, a_r, row, deg, rank, h_bf, el, er);
    k_scan_local<<<SB, 256, 0, stream>>>(deg, rowptr, blocksum);
    k_scan_add  <<<SB, 256, 0, stream>>>(blocksum, rowptr);
    k_fill      <<<EDGE_BLOCKS, 256, 0, stream>>>(row, col, rank, rowptr, csr_col);
    k_gather    <<<N_NODES / 4, 256, 0, stream>>>(rowptr, csr_col, el, er, h_bf, b, out);
}

// Round 10
// 93.539 us; speedup vs baseline: 3.3357x; 1.3829x over previous
//
#include <hip/hip_runtime.h>

#define N_NODES 50000
#define N_EDGES 800000
#define IN_F    128
#define OUT_F   64
#define N_HEADS 4
#define NEG_SLOPE 0.2f
#define EPS 1e-12f

#define NODE_BLOCKS 782   // ceil(50000 / 64) for the MFMA kernel
#define NB   196          // buckets: bucket = row >> 8 (256 nodes each)
#define NCH  784          // edge chunks of 1024: 784*1024 = 802816 >= 800000
#define S2N  (NB * NCH)   // 153664 histogram entries
#define S2B  151          // scan blocks: 151*1024 = 154624 >= S2N

typedef __attribute__((ext_vector_type(8))) short bf16x8;
typedef __attribute__((ext_vector_type(4))) float f32x4;

// bf16 helpers (RNE)
__device__ __forceinline__ unsigned short f2bf(float f) {
    unsigned int u = __float_as_uint(f);
    u += 0x7FFFu + ((u >> 16) & 1u);
    return (unsigned short)(u >> 16);
}

// ---------------------------------------------------------------------------
// K0: blocks 0-3: Wt[c][k] = bf16(W[k][c]); blocks 4..787: per-chunk bucket
// histogram of row[] into histG[bucket*NCH + chunk] (LDS atomics only).
// ---------------------------------------------------------------------------
__global__ __launch_bounds__(256) void k_init(
    const float* __restrict__ W, unsigned short* __restrict__ Wt,
    const int* __restrict__ row, int* __restrict__ histG)
{
    __shared__ int hist[NB];
    const int bb = blockIdx.x;
    const int t = threadIdx.x;
    if (bb < 4) {
        int i = bb * 256 + t;
        for (; i < OUT_F * IN_F; i += 4 * 256) {
            int c = i >> 7, k = i & 127;
            Wt[i] = f2bf(W[k * OUT_F + c]);
        }
        return;
    }
    const int ch = bb - 4;
    if (t < NB) hist[t] = 0;
    __syncthreads();
    const int e0 = ch * 1024 + t * 4;
    if (e0 + 3 < N_EDGES) {
        int4 r4 = *(const int4*)(row + e0);
        atomicAdd(&hist[r4.x >> 8], 1);
        atomicAdd(&hist[r4.y >> 8], 1);
        atomicAdd(&hist[r4.z >> 8], 1);
        atomicAdd(&hist[r4.w >> 8], 1);
    } else {
        #pragma unroll
        for (int j = 0; j < 4; ++j)
            if (e0 + j < N_EDGES) atomicAdd(&hist[row[e0 + j] >> 8], 1);
    }
    __syncthreads();
    if (t < NB) histG[t * NCH + ch] = hist[t];
}

// ---------------------------------------------------------------------------
// K1: h = x @ W via MFMA bf16; fused el = h@a_l, er = h@a_r (f32 epilogue).
// LDS tiles bf16 [64][128], XOR-swizzled (byte ^= (row&7)<<4).
// MFMA C/D: col = l&15, row = (l>>4)*4 + reg  [verified mapping].
// ---------------------------------------------------------------------------
__global__ __launch_bounds__(256) void k_h_el_er(
    const float* __restrict__ x, const unsigned short* __restrict__ Wt,
    const float* __restrict__ a_l, const float* __restrict__ a_r,
    unsigned short* __restrict__ h_bf,
    float* __restrict__ el, float* __restrict__ er)
{
    __shared__ unsigned short xs[64 * 128];   // 16 KB, swizzled
    __shared__ unsigned short wsh[64 * 128];  // 16 KB, swizzled
    const int tid = threadIdx.x;
    const int node0 = blockIdx.x * 64;

    {
        const uint4* src = (const uint4*)Wt;
        #pragma unroll
        for (int j = 0; j < 4; ++j) {
            int idx = tid + 256 * j;
            int r = idx >> 4;
            int cb = (idx & 15) << 4;
            uint4 v = src[idx];
            *(uint4*)((char*)wsh + r * 256 + (cb ^ ((r & 7) << 4))) = v;
        }
    }
    {
        const int r = tid >> 2;
        const int c0 = (tid & 3) * 32;
        const int node = node0 + r;
        unsigned int pk[16];
        if (node < N_NODES) {
            const float* src = x + (size_t)node * IN_F + c0;
            #pragma unroll
            for (int i = 0; i < 8; ++i) {
                float4 v = *(const float4*)(src + 4 * i);
                pk[2 * i + 0] = (unsigned)f2bf(v.x) | ((unsigned)f2bf(v.y) << 16);
                pk[2 * i + 1] = (unsigned)f2bf(v.z) | ((unsigned)f2bf(v.w) << 16);
            }
        } else {
            #pragma unroll
            for (int i = 0; i < 16; ++i) pk[i] = 0;
        }
        #pragma unroll
        for (int q = 0; q < 4; ++q) {
            int cb = c0 * 2 + q * 16;
            *(uint4*)((char*)xs + r * 256 + (cb ^ ((r & 7) << 4))) =
                make_uint4(pk[4 * q], pk[4 * q + 1], pk[4 * q + 2], pk[4 * q + 3]);
        }
    }
    __syncthreads();

    const int w  = tid >> 6, l = tid & 63;
    const int lr = l & 15, lg = l >> 4;
    const int arow = w * 16 + lr;

    bf16x8 afr[4];
    #pragma unroll
    for (int t = 0; t < 4; ++t) {
        int cb = t * 64 + lg * 16;
        afr[t] = *(const bf16x8*)((char*)xs + arow * 256 + (cb ^ ((arow & 7) << 4)));
    }

    const f32x4 zero = {0.f, 0.f, 0.f, 0.f};
    f32x4 acc[4] = {zero, zero, zero, zero};
    #pragma unroll
    for (int nt = 0; nt < 4; ++nt) {
        const int brow = nt * 16 + lr;
        #pragma unroll
        for (int t = 0; t < 4; ++t) {
            int cb = t * 64 + lg * 16;
            bf16x8 bfr = *(const bf16x8*)((char*)wsh + brow * 256 + (cb ^ ((brow & 7) << 4)));
            acc[nt] = __builtin_amdgcn_mfma_f32_16x16x32_bf16(afr[t], bfr, acc[nt], 0, 0, 0);
        }
    }

    #pragma unroll
    for (int r = 0; r < 4; ++r) {
        const int node = node0 + w * 16 + lg * 4 + r;
        if (node < N_NODES) {
            #pragma unroll
            for (int nt = 0; nt < 4; ++nt)
                h_bf[(size_t)node * OUT_F + nt * 16 + lr] = f2bf(acc[nt][r]);
        }
    }

    float4 al4[4], ar4[4];
    #pragma unroll
    for (int nt = 0; nt < 4; ++nt) {
        al4[nt] = *(const float4*)(a_l + (size_t)(nt * 16 + lr) * N_HEADS);
        ar4[nt] = *(const float4*)(a_r + (size_t)(nt * 16 + lr) * N_HEADS);
    }
    #pragma unroll
    for (int r = 0; r < 4; ++r) {
        float4 pl = make_float4(0.f, 0.f, 0.f, 0.f);
        float4 pr = make_float4(0.f, 0.f, 0.f, 0.f);
        #pragma unroll
        for (int nt = 0; nt < 4; ++nt) {
            const float v = acc[nt][r];
            pl.x += v * al4[nt].x; pl.y += v * al4[nt].y;
            pl.z += v * al4[nt].z; pl.w += v * al4[nt].w;
            pr.x += v * ar4[nt].x; pr.y += v * ar4[nt].y;
            pr.z += v * ar4[nt].z; pr.w += v * ar4[nt].w;
        }
        #pragma unroll
        for (int off = 1; off < 16; off <<= 1) {
            pl.x += __shfl_xor(pl.x, off); pl.y += __shfl_xor(pl.y, off);
            pl.z += __shfl_xor(pl.z, off); pl.w += __shfl_xor(pl.w, off);
            pr.x += __shfl_xor(pr.x, off); pr.y += __shfl_xor(pr.y, off);
            pr.z += __shfl_xor(pr.z, off); pr.w += __shfl_xor(pr.w, off);
        }
        const int node = node0 + w * 16 + lg * 4 + r;
        if (lr == 0 && node < N_NODES) {
            *(float4*)(el + (size_t)node * N_HEADS) = pl;
            *(float4*)(er + (size_t)node * N_HEADS) = pr;
        }
    }
}

// ---------------------------------------------------------------------------
// S2a: per-block exclusive scan (1024 elems/block) of histG -> scanHist
// ---------------------------------------------------------------------------
__global__ __launch_bounds__(256) void k_scan2_local(
    const int* __restrict__ histG, int* __restrict__ scanHist,
    int* __restrict__ blocksum)
{
    __shared__ int wsum[4];
    const int t = threadIdx.x;
    const int base = blockIdx.x * 1024 + t * 4;

    int4 d = make_int4(0, 0, 0, 0);
    if (base + 3 < S2N) d = *(const int4*)(histG + base);
    else {
        if (base + 0 < S2N) d.x = histG[base + 0];
        if (base + 1 < S2N) d.y = histG[base + 1];
        if (base + 2 < S2N) d.z = histG[base + 2];
        if (base + 3 < S2N) d.w = histG[base + 3];
    }
    const int tsum = d.x + d.y + d.z + d.w;

    const int lane = t & 63, wave = t >> 6;
    int inc = tsum;
    #pragma unroll
    for (int off = 1; off < 64; off <<= 1) {
        int v = __shfl_up(inc, off);
        if (lane >= off) inc += v;
    }
    if (lane == 63) wsum[wave] = inc;
    __syncthreads();

    int woff = 0;
    #pragma unroll
    for (int w = 0; w < 4; ++w) woff += (w < wave) ? wsum[w] : 0;

    const int ex = woff + inc - tsum;
    int4 o;
    o.x = ex; o.y = ex + d.x; o.z = o.y + d.y; o.w = o.z + d.z;
    if (base + 3 < S2N) *(int4*)(scanHist + base) = o;
    else {
        if (base + 0 < S2N) scanHist[base + 0] = o.x;
        if (base + 1 < S2N) scanHist[base + 1] = o.y;
        if (base + 2 < S2N) scanHist[base + 2] = o.z;
        if (base + 3 < S2N) scanHist[base + 3] = o.w;
    }
    if (t == 0) blocksum[blockIdx.x] = wsum[0] + wsum[1] + wsum[2] + wsum[3];
}

// ---------------------------------------------------------------------------
// S2b: add preceding-block offsets into scanHist
// ---------------------------------------------------------------------------
__global__ __launch_bounds__(256) void k_scan2_add(
    const int* __restrict__ blocksum, int* __restrict__ scanHist)
{
    const int bb = blockIdx.x;
    int off = 0;
    for (int i = 0; i < bb; ++i) off += blocksum[i];
    if (off == 0) return;

    const int t = threadIdx.x;
    const int base = bb * 1024 + t * 4;
    if (base + 3 < S2N) {
        int4 v = *(int4*)(scanHist + base);
        v.x += off; v.y += off; v.z += off; v.w += off;
        *(int4*)(scanHist + base) = v;
    } else {
        if (base + 0 < S2N) scanHist[base + 0] += off;
        if (base + 1 < S2N) scanHist[base + 1] += off;
        if (base + 2 < S2N) scanHist[base + 2] += off;
        if (base + 3 < S2N) scanHist[base + 3] += off;
    }
}

// ---------------------------------------------------------------------------
// S3: bucket-scatter edges. Per chunk: LDS write cursors from scanHist,
// LDS-atomic slot allocation, store packed (row&255)<<17 | col.
// ---------------------------------------------------------------------------
__global__ __launch_bounds__(256) void k_scatter(
    const int* __restrict__ row, const int* __restrict__ col,
    const int* __restrict__ scanHist, unsigned* __restrict__ ebuf)
{
    __shared__ int off[NB];
    const int ch = blockIdx.x;
    const int t = threadIdx.x;
    if (t < NB) off[t] = scanHist[t * NCH + ch];
    __syncthreads();
    const int e0 = ch * 1024;
    #pragma unroll
    for (int k = 0; k < 4; ++k) {
        const int e = e0 + t + k * 256;
        if (e < N_EDGES) {
            const int r = row[e], c = col[e];
            const int pos = atomicAdd(&off[r >> 8], 1);
            ebuf[pos] = ((unsigned)(r & 255) << 17) | (unsigned)c;
        }
    }
}

// ---------------------------------------------------------------------------
// S4: per-bucket CSR finalize. Count 256 local rows (LDS), 256-wide scan,
// write rowptr, then scatter cols into csr_col (bucket-local region).
// ---------------------------------------------------------------------------
__global__ __launch_bounds__(256) void k_bucket(
    const unsigned* __restrict__ ebuf, const int* __restrict__ scanHist,
    int* __restrict__ rowptr, int* __restrict__ csr_col)
{
    __shared__ int cnt[256];
    __shared__ int wsum[4];
    const int b = blockIdx.x;
    const int t = threadIdx.x;
    const int base = scanHist[b * NCH];
    const int end  = (b < NB - 1) ? scanHist[(b + 1) * NCH] : N_EDGES;

    cnt[t] = 0;
    __syncthreads();
    for (int i = base + t; i < end; i += 256)
        atomicAdd(&cnt[ebuf[i] >> 17], 1);
    __syncthreads();

    const int val = cnt[t];
    const int lane = t & 63, wave = t >> 6;
    int inc = val;
    #pragma unroll
    for (int off = 1; off < 64; off <<= 1) {
        int v = __shfl_up(inc, off);
        if (lane >= off) inc += v;
    }
    if (lane == 63) wsum[wave] = inc;
    __syncthreads();
    int woff = 0;
    #pragma unroll
    for (int w = 0; w < 4; ++w) woff += (w < wave) ? wsum[w] : 0;
    const int excl = base + woff + inc - val;

    const int node = (b << 8) + t;
    if (node < N_NODES) rowptr[node] = excl;
    if (b == NB - 1 && t == 0) rowptr[N_NODES] = N_EDGES;
    __syncthreads();
    cnt[t] = excl;   // reuse as write cursors
    __syncthreads();

    for (int i = base + t; i < end; i += 256) {
        const unsigned p = ebuf[i];
        const int pos = atomicAdd(&cnt[p >> 17], 1);
        csr_col[pos] = (int)(p & 0x1FFFFu);
    }
}

// ---------------------------------------------------------------------------
// K5: gather — one wave per node; 4 x 16-lane groups, 4 edges/iter, with a
// 1-ahead software pipeline on (csr_col -> er, h). 32-bit element offsets.
// ---------------------------------------------------------------------------
__global__ __launch_bounds__(256) void k_gather(
    const int* __restrict__ rowptr, const int* __restrict__ csr_col,
    const float* __restrict__ el, const float* __restrict__ er,
    const unsigned short* __restrict__ h_bf, const float* __restrict__ b,
    float* __restrict__ out)
{
    int n = blockIdx.x * 4 + (threadIdx.x >> 6);
    if (n >= N_NODES) return;
    const int lane = threadIdx.x & 63;
    const int g    = lane >> 4;    // group == output head at the end
    const int fq   = lane & 15;    // feature quad: feats fq*4 .. +3

    const int s0 = rowptr[n], s1 = rowptr[n + 1];
    const int deg = s1 - s0;
    const int nit = (deg + 3) >> 2;

    float acc[4][4];
    #pragma unroll
    for (int hd = 0; hd < 4; ++hd)
        #pragma unroll
        for (int f = 0; f < 4; ++f) acc[hd][f] = 0.f;
    float den[4] = {0.f, 0.f, 0.f, 0.f};

    const float4 elv = *reinterpret_cast<const float4*>(el + ((unsigned)n << 2));

    bool v_cur = false;
    float4 erv_cur = make_float4(0.f, 0.f, 0.f, 0.f);
    uint2  h_cur = make_uint2(0, 0);
    if (nit > 0) {
        const int j = s0 + g;
        v_cur = j < s1;
        const int jc = v_cur ? j : (s1 - 1);
        const int c = csr_col[jc];
        erv_cur = *reinterpret_cast<const float4*>(er + ((unsigned)c << 2));
        h_cur   = *reinterpret_cast<const uint2*>(h_bf + (((unsigned)c << 6) + (fq << 2)));
    }

    for (int it = 0; it < nit; ++it) {
        bool v_nx = false;
        float4 erv_nx = make_float4(0.f, 0.f, 0.f, 0.f);
        uint2  h_nx = make_uint2(0, 0);
        if (it + 1 < nit) {
            const int j = s0 + (it + 1) * 4 + g;
            v_nx = j < s1;
            const int jc = v_nx ? j : (s1 - 1);
            const int c = csr_col[jc];
            erv_nx = *reinterpret_cast<const float4*>(er + ((unsigned)c << 2));
            h_nx   = *reinterpret_cast<const uint2*>(h_bf + (((unsigned)c << 6) + (fq << 2)));
        }

        float t0 = elv.x + erv_cur.x, t1 = elv.y + erv_cur.y;
        float t2 = elv.z + erv_cur.z, t3 = elv.w + erv_cur.w;
        t0 = t0 > 0.f ? t0 : NEG_SLOPE * t0;
        t1 = t1 > 0.f ? t1 : NEG_SLOPE * t1;
        t2 = t2 > 0.f ? t2 : NEG_SLOPE * t2;
        t3 = t3 > 0.f ? t3 : NEG_SLOPE * t3;
        float4 w = make_float4(__expf(t0), __expf(t1), __expf(t2), __expf(t3));
        if (!v_cur) w = make_float4(0.f, 0.f, 0.f, 0.f);

        const float h0 = __uint_as_float(h_cur.x << 16);
        const float h1 = __uint_as_float(h_cur.x & 0xFFFF0000u);
        const float h2 = __uint_as_float(h_cur.y << 16);
        const float h3 = __uint_as_float(h_cur.y & 0xFFFF0000u);

        den[0] += w.x; den[1] += w.y; den[2] += w.z; den[3] += w.w;
        acc[0][0] += w.x * h0; acc[0][1] += w.x * h1; acc[0][2] += w.x * h2; acc[0][3] += w.x * h3;
        acc[1][0] += w.y * h0; acc[1][1] += w.y * h1; acc[1][2] += w.y * h2; acc[1][3] += w.y * h3;
        acc[2][0] += w.z * h0; acc[2][1] += w.z * h1; acc[2][2] += w.z * h2; acc[2][3] += w.z * h3;
        acc[3][0] += w.w * h0; acc[3][1] += w.w * h1; acc[3][2] += w.w * h2; acc[3][3] += w.w * h3;

        v_cur = v_nx; erv_cur = erv_nx; h_cur = h_nx;
    }

    #pragma unroll
    for (int hd = 0; hd < 4; ++hd) {
        float v = den[hd];
        v += __shfl_xor(v, 16); v += __shfl_xor(v, 32);
        den[hd] = v;
        #pragma unroll
        for (int f = 0; f < 4; ++f) {
            float u = acc[hd][f];
            u += __shfl_xor(u, 16); u += __shfl_xor(u, 32);
            acc[hd][f] = u;
        }
    }

    const float dg = g == 0 ? den[0] : g == 1 ? den[1] : g == 2 ? den[2] : den[3];
    const float inv = 1.f / fmaxf(dg, EPS);
    float4 o;
    o.x = (g == 0 ? acc[0][0] : g == 1 ? acc[1][0] : g == 2 ? acc[2][0] : acc[3][0]);
    o.y = (g == 0 ? acc[0][1] : g == 1 ? acc[1][1] : g == 2 ? acc[2][1] : acc[3][1]);
    o.z = (g == 0 ? acc[0][2] : g == 1 ? acc[1][2] : g == 2 ? acc[2][2] : acc[3][2]);
    o.w = (g == 0 ? acc[0][3] : g == 1 ? acc[1][3] : g == 2 ? acc[2][3] : acc[3][3]);

    const float4 bias = *(const float4*)(b + fq * 4);
    o.x = o.x * inv + bias.x;
    o.y = o.y * inv + bias.y;
    o.z = o.z * inv + bias.z;
    o.w = o.w * inv + bias.w;
    *(float4*)(out + (size_t)n * (N_HEADS * OUT_F) + g * 64 + fq * 4) = o;
}

extern "C" void kernel_launch(void* const* d_in, const int* in_sizes, int n_in,
                              void* d_out, int out_size, void* d_ws, size_t ws_size,
                              hipStream_t stream)
{
    const float* x   = (const float*)d_in[0];
    const int*   ei  = (const int*)d_in[1];
    const float* W   = (const float*)d_in[2];
    const float* a_l = (const float*)d_in[3];
    const float* a_r = (const float*)d_in[4];
    const float* b   = (const float*)d_in[5];
    float* out = (float*)d_out;

    char* ws = (char*)d_ws;
    unsigned short* h_bf = (unsigned short*)(ws);          //  6,400,000 B
    float*    el       = (float*)   (ws +  6400000);       //    800,000 B
    float*    er       = (float*)   (ws +  7200000);       //    800,000 B
    unsigned short* Wt = (unsigned short*)(ws + 8000000);  //     16,384 B
    int*      histG    = (int*)     (ws +  8016384);       //    614,656 B
    int*      scanHist = (int*)     (ws +  8631040);       //    614,656 B
    int*      blocksum = (int*)     (ws +  9245696);       //      1,024 B
    unsigned* ebuf     = (unsigned*)(ws +  9246720);       //  3,200,000 B
    int*      csr_col  = (int*)     (ws + 12446720);       //  3,200,000 B
    int*      rowptr   = (int*)     (ws + 15646720);       //    200,016 B

    const int* row = ei;
    const int* col = ei + N_EDGES;

    k_init      <<<4 + NCH, 256, 0, stream>>>(W, Wt, row, histG);
    k_h_el_er   <<<NODE_BLOCKS, 256, 0, stream>>>(x, Wt, a_l, a_r, h_bf, el, er);
    k_scan2_local<<<S2B, 256, 0, stream>>>(histG, scanHist, blocksum);
    k_scan2_add <<<S2B, 256, 0, stream>>>(blocksum, scanHist);
    k_scatter   <<<NCH, 256, 0, stream>>>(row, col, scanHist, ebuf);
    k_bucket    <<<NB, 256, 0, stream>>>(ebuf, scanHist, rowptr, csr_col);
    k_gather    <<<N_NODES / 4, 256, 0, stream>>>(rowptr, csr_col, el, er, h_bf, b, out);
}

// Round 11
// 92.811 us; speedup vs baseline: 3.3619x; 1.0079x over previous
//
#include <hip/hip_runtime.h>

#define N_NODES 50000
#define N_EDGES 800000
#define IN_F    128
#define OUT_F   64
#define N_HEADS 4
#define NEG_SLOPE 0.2f
#define EPS 1e-12f

#define NODE_BLOCKS 782   // ceil(50000 / 64) for the MFMA kernel
#define NB    391         // buckets of 128 rows: bucket = row >> 7
#define CHUNK 2048        // edges per histogram/scatter chunk
#define NCH   391         // 391*2048 = 800768 >= 800000
#define S2N   (NB * NCH)  // 152881 histogram entries
#define S2B   150         // scan blocks: 150*1024 = 153600 >= S2N

typedef __attribute__((ext_vector_type(8))) short bf16x8;
typedef __attribute__((ext_vector_type(4))) float f32x4;

// bf16 helpers (RNE)
__device__ __forceinline__ unsigned short f2bf(float f) {
    unsigned int u = __float_as_uint(f);
    u += 0x7FFFu + ((u >> 16) & 1u);
    return (unsigned short)(u >> 16);
}

// ---------------------------------------------------------------------------
// K0: blocks 0-3: Wt[c][k] = bf16(W[k][c]); blocks 4..394: per-chunk bucket
// histogram of row[] into histG[bucket*NCH + chunk] (LDS atomics only).
// ---------------------------------------------------------------------------
__global__ __launch_bounds__(256) void k_init(
    const float* __restrict__ W, unsigned short* __restrict__ Wt,
    const int* __restrict__ row, int* __restrict__ histG)
{
    __shared__ int hist[NB];
    const int bb = blockIdx.x;
    const int t = threadIdx.x;
    if (bb < 4) {
        int i = bb * 256 + t;
        for (; i < OUT_F * IN_F; i += 4 * 256) {
            int c = i >> 7, k = i & 127;
            Wt[i] = f2bf(W[k * OUT_F + c]);
        }
        return;
    }
    const int ch = bb - 4;
    for (int i = t; i < NB; i += 256) hist[i] = 0;
    __syncthreads();
    const int e0 = ch * CHUNK + t * 8;
    if (e0 + 7 < N_EDGES) {
        int4 a = *(const int4*)(row + e0);
        int4 c = *(const int4*)(row + e0 + 4);
        atomicAdd(&hist[a.x >> 7], 1); atomicAdd(&hist[a.y >> 7], 1);
        atomicAdd(&hist[a.z >> 7], 1); atomicAdd(&hist[a.w >> 7], 1);
        atomicAdd(&hist[c.x >> 7], 1); atomicAdd(&hist[c.y >> 7], 1);
        atomicAdd(&hist[c.z >> 7], 1); atomicAdd(&hist[c.w >> 7], 1);
    } else {
        #pragma unroll
        for (int j = 0; j < 8; ++j)
            if (e0 + j < N_EDGES) atomicAdd(&hist[row[e0 + j] >> 7], 1);
    }
    __syncthreads();
    for (int i = t; i < NB; i += 256) histG[i * NCH + ch] = hist[i];
}

// ---------------------------------------------------------------------------
// K1: h = x @ W via MFMA bf16; fused el = h@a_l, er = h@a_r (f32 epilogue).
// LDS tiles bf16 [64][128], XOR-swizzled (byte ^= (row&7)<<4).
// MFMA C/D: col = l&15, row = (l>>4)*4 + reg  [verified mapping].
// ---------------------------------------------------------------------------
__global__ __launch_bounds__(256) void k_h_el_er(
    const float* __restrict__ x, const unsigned short* __restrict__ Wt,
    const float* __restrict__ a_l, const float* __restrict__ a_r,
    unsigned short* __restrict__ h_bf,
    float* __restrict__ el, float* __restrict__ er)
{
    __shared__ unsigned short xs[64 * 128];   // 16 KB, swizzled
    __shared__ unsigned short wsh[64 * 128];  // 16 KB, swizzled
    const int tid = threadIdx.x;
    const int node0 = blockIdx.x * 64;

    {
        const uint4* src = (const uint4*)Wt;
        #pragma unroll
        for (int j = 0; j < 4; ++j) {
            int idx = tid + 256 * j;
            int r = idx >> 4;
            int cb = (idx & 15) << 4;
            uint4 v = src[idx];
            *(uint4*)((char*)wsh + r * 256 + (cb ^ ((r & 7) << 4))) = v;
        }
    }
    {
        const int r = tid >> 2;
        const int c0 = (tid & 3) * 32;
        const int node = node0 + r;
        unsigned int pk[16];
        if (node < N_NODES) {
            const float* src = x + (size_t)node * IN_F + c0;
            #pragma unroll
            for (int i = 0; i < 8; ++i) {
                float4 v = *(const float4*)(src + 4 * i);
                pk[2 * i + 0] = (unsigned)f2bf(v.x) | ((unsigned)f2bf(v.y) << 16);
                pk[2 * i + 1] = (unsigned)f2bf(v.z) | ((unsigned)f2bf(v.w) << 16);
            }
        } else {
            #pragma unroll
            for (int i = 0; i < 16; ++i) pk[i] = 0;
        }
        #pragma unroll
        for (int q = 0; q < 4; ++q) {
            int cb = c0 * 2 + q * 16;
            *(uint4*)((char*)xs + r * 256 + (cb ^ ((r & 7) << 4))) =
                make_uint4(pk[4 * q], pk[4 * q + 1], pk[4 * q + 2], pk[4 * q + 3]);
        }
    }
    __syncthreads();

    const int w  = tid >> 6, l = tid & 63;
    const int lr = l & 15, lg = l >> 4;
    const int arow = w * 16 + lr;

    bf16x8 afr[4];
    #pragma unroll
    for (int t = 0; t < 4; ++t) {
        int cb = t * 64 + lg * 16;
        afr[t] = *(const bf16x8*)((char*)xs + arow * 256 + (cb ^ ((arow & 7) << 4)));
    }

    const f32x4 zero = {0.f, 0.f, 0.f, 0.f};
    f32x4 acc[4] = {zero, zero, zero, zero};
    #pragma unroll
    for (int nt = 0; nt < 4; ++nt) {
        const int brow = nt * 16 + lr;
        #pragma unroll
        for (int t = 0; t < 4; ++t) {
            int cb = t * 64 + lg * 16;
            bf16x8 bfr = *(const bf16x8*)((char*)wsh + brow * 256 + (cb ^ ((brow & 7) << 4)));
            acc[nt] = __builtin_amdgcn_mfma_f32_16x16x32_bf16(afr[t], bfr, acc[nt], 0, 0, 0);
        }
    }

    #pragma unroll
    for (int r = 0; r < 4; ++r) {
        const int node = node0 + w * 16 + lg * 4 + r;
        if (node < N_NODES) {
            #pragma unroll
            for (int nt = 0; nt < 4; ++nt)
                h_bf[(size_t)node * OUT_F + nt * 16 + lr] = f2bf(acc[nt][r]);
        }
    }

    float4 al4[4], ar4[4];
    #pragma unroll
    for (int nt = 0; nt < 4; ++nt) {
        al4[nt] = *(const float4*)(a_l + (size_t)(nt * 16 + lr) * N_HEADS);
        ar4[nt] = *(const float4*)(a_r + (size_t)(nt * 16 + lr) * N_HEADS);
    }
    #pragma unroll
    for (int r = 0; r < 4; ++r) {
        float4 pl = make_float4(0.f, 0.f, 0.f, 0.f);
        float4 pr = make_float4(0.f, 0.f, 0.f, 0.f);
        #pragma unroll
        for (int nt = 0; nt < 4; ++nt) {
            const float v = acc[nt][r];
            pl.x += v * al4[nt].x; pl.y += v * al4[nt].y;
            pl.z += v * al4[nt].z; pl.w += v * al4[nt].w;
            pr.x += v * ar4[nt].x; pr.y += v * ar4[nt].y;
            pr.z += v * ar4[nt].z; pr.w += v * ar4[nt].w;
        }
        #pragma unroll
        for (int off = 1; off < 16; off <<= 1) {
            pl.x += __shfl_xor(pl.x, off); pl.y += __shfl_xor(pl.y, off);
            pl.z += __shfl_xor(pl.z, off); pl.w += __shfl_xor(pl.w, off);
            pr.x += __shfl_xor(pr.x, off); pr.y += __shfl_xor(pr.y, off);
            pr.z += __shfl_xor(pr.z, off); pr.w += __shfl_xor(pr.w, off);
        }
        const int node = node0 + w * 16 + lg * 4 + r;
        if (lr == 0 && node < N_NODES) {
            *(float4*)(el + (size_t)node * N_HEADS) = pl;
            *(float4*)(er + (size_t)node * N_HEADS) = pr;
        }
    }
}

// ---------------------------------------------------------------------------
// S2a: per-block exclusive scan (1024 elems/block) of histG -> scanHist
// ---------------------------------------------------------------------------
__global__ __launch_bounds__(256) void k_scan2_local(
    const int* __restrict__ histG, int* __restrict__ scanHist,
    int* __restrict__ blocksum)
{
    __shared__ int wsum[4];
    const int t = threadIdx.x;
    const int base = blockIdx.x * 1024 + t * 4;

    int4 d = make_int4(0, 0, 0, 0);
    if (base + 3 < S2N) d = *(const int4*)(histG + base);
    else {
        if (base + 0 < S2N) d.x = histG[base + 0];
        if (base + 1 < S2N) d.y = histG[base + 1];
        if (base + 2 < S2N) d.z = histG[base + 2];
        if (base + 3 < S2N) d.w = histG[base + 3];
    }
    const int tsum = d.x + d.y + d.z + d.w;

    const int lane = t & 63, wave = t >> 6;
    int inc = tsum;
    #pragma unroll
    for (int off = 1; off < 64; off <<= 1) {
        int v = __shfl_up(inc, off);
        if (lane >= off) inc += v;
    }
    if (lane == 63) wsum[wave] = inc;
    __syncthreads();

    int woff = 0;
    #pragma unroll
    for (int w = 0; w < 4; ++w) woff += (w < wave) ? wsum[w] : 0;

    const int ex = woff + inc - tsum;
    int4 o;
    o.x = ex; o.y = ex + d.x; o.z = o.y + d.y; o.w = o.z + d.z;
    if (base + 3 < S2N) *(int4*)(scanHist + base) = o;
    else {
        if (base + 0 < S2N) scanHist[base + 0] = o.x;
        if (base + 1 < S2N) scanHist[base + 1] = o.y;
        if (base + 2 < S2N) scanHist[base + 2] = o.z;
        if (base + 3 < S2N) scanHist[base + 3] = o.w;
    }
    if (t == 0) blocksum[blockIdx.x] = wsum[0] + wsum[1] + wsum[2] + wsum[3];
}

// ---------------------------------------------------------------------------
// S2b: add preceding-block offsets into scanHist
// ---------------------------------------------------------------------------
__global__ __launch_bounds__(256) void k_scan2_add(
    const int* __restrict__ blocksum, int* __restrict__ scanHist)
{
    const int bb = blockIdx.x;
    int off = 0;
    for (int i = 0; i < bb; ++i) off += blocksum[i];
    if (off == 0) return;

    const int t = threadIdx.x;
    const int base = bb * 1024 + t * 4;
    if (base + 3 < S2N) {
        int4 v = *(int4*)(scanHist + base);
        v.x += off; v.y += off; v.z += off; v.w += off;
        *(int4*)(scanHist + base) = v;
    } else {
        if (base + 0 < S2N) scanHist[base + 0] += off;
        if (base + 1 < S2N) scanHist[base + 1] += off;
        if (base + 2 < S2N) scanHist[base + 2] += off;
        if (base + 3 < S2N) scanHist[base + 3] += off;
    }
}

// ---------------------------------------------------------------------------
// S3: bucket-scatter edges. Per chunk: LDS write cursors from scanHist,
// LDS-atomic slot allocation, store packed (row&127)<<17 | col.
// ---------------------------------------------------------------------------
__global__ __launch_bounds__(256) void k_scatter(
    const int* __restrict__ row, const int* __restrict__ col,
    const int* __restrict__ scanHist, unsigned* __restrict__ ebuf)
{
    __shared__ int off[NB];
    const int ch = blockIdx.x;
    const int t = threadIdx.x;
    for (int i = t; i < NB; i += 256) off[i] = scanHist[i * NCH + ch];
    __syncthreads();
    const int e0 = ch * CHUNK;
    #pragma unroll
    for (int k = 0; k < 8; ++k) {
        const int e = e0 + t + k * 256;
        if (e < N_EDGES) {
            const int r = row[e], c = col[e];
            const int pos = atomicAdd(&off[r >> 7], 1);
            ebuf[pos] = ((unsigned)(r & 127) << 17) | (unsigned)c;
        }
    }
}

// ---------------------------------------------------------------------------
// S4: per-bucket CSR finalize. Count 128 local rows (LDS), scan, write
// rowptr; then scatter cols AND precomputed exp weights (f32x4) into the
// bucket-local region (single block -> single XCD -> no write-amp).
// ---------------------------------------------------------------------------
__global__ __launch_bounds__(256) void k_bucket(
    const unsigned* __restrict__ ebuf, const int* __restrict__ scanHist,
    const float* __restrict__ el, const float* __restrict__ er,
    int* __restrict__ rowptr, int* __restrict__ csr_col,
    float4* __restrict__ csr_w)
{
    __shared__ float4 elv[128];
    __shared__ int cnt[128];
    __shared__ int wsum2[2];
    const int b = blockIdx.x;
    const int t = threadIdx.x;
    const int node0 = b << 7;
    const int base = scanHist[b * NCH];
    const int end  = (b < NB - 1) ? scanHist[(b + 1) * NCH] : N_EDGES;

    if (t < 128) {
        const int node = node0 + t;
        elv[t] = (node < N_NODES) ? *(const float4*)(el + node * 4)
                                  : make_float4(0.f, 0.f, 0.f, 0.f);
        cnt[t] = 0;
    }
    __syncthreads();
    for (int i = base + t; i < end; i += 256)
        atomicAdd(&cnt[ebuf[i] >> 17], 1);
    __syncthreads();

    int inc = 0, val = 0;
    const int lane = t & 63, wave = t >> 6;
    if (t < 128) {
        val = cnt[t];
        inc = val;
        #pragma unroll
        for (int off = 1; off < 64; off <<= 1) {
            int v = __shfl_up(inc, off);
            if (lane >= off) inc += v;
        }
        if (lane == 63) wsum2[wave] = inc;
    }
    __syncthreads();
    int excl = 0;
    if (t < 128) {
        const int woff = (wave == 1) ? wsum2[0] : 0;
        excl = base + woff + inc - val;
        const int node = node0 + t;
        if (node < N_NODES) rowptr[node] = excl;
    }
    if (b == NB - 1 && t == 0) rowptr[N_NODES] = N_EDGES;
    __syncthreads();
    if (t < 128) cnt[t] = excl;   // reuse as write cursors
    __syncthreads();

    for (int i = base + t; i < end; i += 256) {
        const unsigned p = ebuf[i];
        const int r = p >> 17;
        const int c = (int)(p & 0x1FFFFu);
        const int pos = atomicAdd(&cnt[r], 1);
        const float4 e4 = elv[r];
        const float4 r4 = *(const float4*)(er + ((unsigned)c << 2));
        float s0 = e4.x + r4.x, s1 = e4.y + r4.y;
        float s2 = e4.z + r4.z, s3 = e4.w + r4.w;
        s0 = s0 > 0.f ? s0 : NEG_SLOPE * s0;
        s1 = s1 > 0.f ? s1 : NEG_SLOPE * s1;
        s2 = s2 > 0.f ? s2 : NEG_SLOPE * s2;
        s3 = s3 > 0.f ? s3 : NEG_SLOPE * s3;
        csr_col[pos] = c;
        csr_w[pos] = make_float4(__expf(s0), __expf(s1), __expf(s2), __expf(s3));
    }
}

// ---------------------------------------------------------------------------
// K5: gather — one wave per node; 4 x 16-lane groups, 4 edges/iter, 2-deep
// software pipeline on (csr_col -> csr_w, h). No attention math in-loop.
// Invalid slots contribute w=0, h=0 (exec-masked loads; no NaN path).
// ---------------------------------------------------------------------------
__global__ __launch_bounds__(256) void k_gather(
    const int* __restrict__ rowptr, const int* __restrict__ csr_col,
    const float4* __restrict__ csr_w,
    const unsigned short* __restrict__ h_bf, const float* __restrict__ b,
    float* __restrict__ out)
{
    int n = blockIdx.x * 4 + (threadIdx.x >> 6);
    if (n >= N_NODES) return;
    const int lane = threadIdx.x & 63;
    const int g    = lane >> 4;    // group == output head at the end
    const int fq   = lane & 15;    // feature quad: feats fq*4 .. +3

    const int s0 = rowptr[n], s1 = rowptr[n + 1];
    const int nit = (s1 - s0 + 3) >> 2;

    float acc[4][4];
    #pragma unroll
    for (int hd = 0; hd < 4; ++hd)
        #pragma unroll
        for (int f = 0; f < 4; ++f) acc[hd][f] = 0.f;
    float den[4] = {0.f, 0.f, 0.f, 0.f};

#define GLOAD(ii, WV, HV)                                                  \
    {                                                                      \
        WV = make_float4(0.f, 0.f, 0.f, 0.f);                              \
        HV = make_uint2(0u, 0u);                                           \
        const int j = s0 + (ii) * 4 + g;                                   \
        if ((ii) < nit && j < s1) {                                        \
            const int c = csr_col[j];                                      \
            WV = csr_w[j];                                                 \
            HV = *(const uint2*)(h_bf + (((unsigned)c << 6) + (fq << 2))); \
        }                                                                  \
    }

    float4 w0, w1; uint2 h0, h1;
    GLOAD(0, w0, h0);
    GLOAD(1, w1, h1);

    for (int it = 0; it < nit; ++it) {
        float4 w2; uint2 h2;
        GLOAD(it + 2, w2, h2);

        const float f0 = __uint_as_float(h0.x << 16);
        const float f1 = __uint_as_float(h0.x & 0xFFFF0000u);
        const float f2 = __uint_as_float(h0.y << 16);
        const float f3 = __uint_as_float(h0.y & 0xFFFF0000u);

        den[0] += w0.x; den[1] += w0.y; den[2] += w0.z; den[3] += w0.w;
        acc[0][0] += w0.x * f0; acc[0][1] += w0.x * f1; acc[0][2] += w0.x * f2; acc[0][3] += w0.x * f3;
        acc[1][0] += w0.y * f0; acc[1][1] += w0.y * f1; acc[1][2] += w0.y * f2; acc[1][3] += w0.y * f3;
        acc[2][0] += w0.z * f0; acc[2][1] += w0.z * f1; acc[2][2] += w0.z * f2; acc[2][3] += w0.z * f3;
        acc[3][0] += w0.w * f0; acc[3][1] += w0.w * f1; acc[3][2] += w0.w * f2; acc[3][3] += w0.w * f3;

        w0 = w1; h0 = h1;
        w1 = w2; h1 = h2;
    }
#undef GLOAD

    // reduce partials across the 4 groups (lanes xor 16, 32)
    #pragma unroll
    for (int hd = 0; hd < 4; ++hd) {
        float v = den[hd];
        v += __shfl_xor(v, 16); v += __shfl_xor(v, 32);
        den[hd] = v;
        #pragma unroll
        for (int f = 0; f < 4; ++f) {
            float u = acc[hd][f];
            u += __shfl_xor(u, 16); u += __shfl_xor(u, 32);
            acc[hd][f] = u;
        }
    }

    const float dg = g == 0 ? den[0] : g == 1 ? den[1] : g == 2 ? den[2] : den[3];
    const float inv = 1.f / fmaxf(dg, EPS);
    float4 o;
    o.x = (g == 0 ? acc[0][0] : g == 1 ? acc[1][0] : g == 2 ? acc[2][0] : acc[3][0]);
    o.y = (g == 0 ? acc[0][1] : g == 1 ? acc[1][1] : g == 2 ? acc[2][1] : acc[3][1]);
    o.z = (g == 0 ? acc[0][2] : g == 1 ? acc[1][2] : g == 2 ? acc[2][2] : acc[3][2]);
    o.w = (g == 0 ? acc[0][3] : g == 1 ? acc[1][3] : g == 2 ? acc[2][3] : acc[3][3]);

    const float4 bias = *(const float4*)(b + fq * 4);
    o.x = o.x * inv + bias.x;
    o.y = o.y * inv + bias.y;
    o.z = o.z * inv + bias.z;
    o.w = o.w * inv + bias.w;
    *(float4*)(out + (size_t)n * (N_HEADS * OUT_F) + g * 64 + fq * 4) = o;
}

extern "C" void kernel_launch(void* const* d_in, const int* in_sizes, int n_in,
                              void* d_out, int out_size, void* d_ws, size_t ws_size,
                              hipStream_t stream)
{
    const float* x   = (const float*)d_in[0];
    const int*   ei  = (const int*)d_in[1];
    const float* W   = (const float*)d_in[2];
    const float* a_l = (const float*)d_in[3];
    const float* a_r = (const float*)d_in[4];
    const float* b   = (const float*)d_in[5];
    float* out = (float*)d_out;

    char* ws = (char*)d_ws;
    unsigned short* h_bf = (unsigned short*)(ws);          //  6,400,000 B
    float*    el       = (float*)   (ws +  6400000);       //    800,000 B
    float*    er       = (float*)   (ws +  7200000);       //    800,000 B
    unsigned short* Wt = (unsigned short*)(ws + 8000000);  //     16,384 B
    int*      histG    = (int*)     (ws +  8016384);       //    611,536 B (S2N*4 rounded)
    int*      scanHist = (int*)     (ws +  8627920);       //    611,536 B
    int*      blocksum = (int*)     (ws +  9239456);       //      1,024 B
    unsigned* ebuf     = (unsigned*)(ws +  9240480);       //  3,200,000 B
    int*      csr_col  = (int*)     (ws + 12440480);       //  3,200,016 B (pad)
    float4*   csr_w    = (float4*)  (ws + 15640496);       // 12,800,000 B
    int*      rowptr   = (int*)     (ws + 28440496);       //    200,016 B
    // total: 28,640,512 B

    const int* row = ei;
    const int* col = ei + N_EDGES;

    k_init       <<<4 + NCH, 256, 0, stream>>>(W, Wt, row, histG);
    k_h_el_er    <<<NODE_BLOCKS, 256, 0, stream>>>(x, Wt, a_l, a_r, h_bf, el, er);
    k_scan2_local<<<S2B, 256, 0, stream>>>(histG, scanHist, blocksum);
    k_scan2_add  <<<S2B, 256, 0, stream>>>(blocksum, scanHist);
    k_scatter    <<<NCH, 256, 0, stream>>>(row, col, scanHist, ebuf);
    k_bucket     <<<NB, 256, 0, stream>>>(ebuf, scanHist, el, er, rowptr, csr_col, csr_w);
    k_gather     <<<N_NODES / 4, 256, 0, stream>>>(rowptr, csr_col, csr_w, h_bf, b, out);
}

// Round 12
// 85.476 us; speedup vs baseline: 3.6504x; 1.0858x over previous
//
#include <hip/hip_runtime.h>

#define N_NODES 50000
#define N_EDGES 800000
#define IN_F    128
#define OUT_F   64
#define N_HEADS 4
#define NEG_SLOPE 0.2f
#define EPS 1e-12f

#define NODE_BLOCKS 782   // ceil(50000 / 64) for the MFMA kernel
#define NB    391         // buckets of 128 rows: bucket = row >> 7
#define CHUNK 4096        // edges per histogram/scatter chunk
#define NCH   196         // 196*4096 = 802816 >= 800000
#define S2N   (NB * NCH)  // 76636 histogram entries
#define S2B   75          // scan blocks: 75*1024 = 76800 >= S2N

typedef __attribute__((ext_vector_type(8))) short bf16x8;
typedef __attribute__((ext_vector_type(4))) float f32x4;

// bf16 helpers (RNE)
__device__ __forceinline__ unsigned short f2bf(float f) {
    unsigned int u = __float_as_uint(f);
    u += 0x7FFFu + ((u >> 16) & 1u);
    return (unsigned short)(u >> 16);
}
__device__ __forceinline__ float bf_lo(unsigned u) { return __uint_as_float(u << 16); }
__device__ __forceinline__ float bf_hi(unsigned u) { return __uint_as_float(u & 0xFFFF0000u); }

// ---------------------------------------------------------------------------
// K0: blocks 0-3: Wt[c][k] = bf16(W[k][c]); blocks 4..199: per-chunk bucket
// histogram of row[] into histG[bucket*NCH + chunk] (LDS atomics only).
// ---------------------------------------------------------------------------
__global__ __launch_bounds__(256) void k_init(
    const float* __restrict__ W, unsigned short* __restrict__ Wt,
    const int* __restrict__ row, int* __restrict__ histG)
{
    __shared__ int hist[NB];
    const int bb = blockIdx.x;
    const int t = threadIdx.x;
    if (bb < 4) {
        int i = bb * 256 + t;
        for (; i < OUT_F * IN_F; i += 4 * 256) {
            int c = i >> 7, k = i & 127;
            Wt[i] = f2bf(W[k * OUT_F + c]);
        }
        return;
    }
    const int ch = bb - 4;
    for (int i = t; i < NB; i += 256) hist[i] = 0;
    __syncthreads();
    const int e0 = ch * CHUNK + t * 16;
    #pragma unroll
    for (int q = 0; q < 4; ++q) {
        const int e = e0 + q * 4;
        if (e + 3 < N_EDGES) {
            int4 a = *(const int4*)(row + e);
            atomicAdd(&hist[a.x >> 7], 1); atomicAdd(&hist[a.y >> 7], 1);
            atomicAdd(&hist[a.z >> 7], 1); atomicAdd(&hist[a.w >> 7], 1);
        } else {
            #pragma unroll
            for (int j = 0; j < 4; ++j)
                if (e + j < N_EDGES) atomicAdd(&hist[row[e + j] >> 7], 1);
        }
    }
    __syncthreads();
    for (int i = t; i < NB; i += 256) histG[i * NCH + ch] = hist[i];
}

// ---------------------------------------------------------------------------
// K1: h = x @ W via MFMA bf16; fused el = h@a_l, er = h@a_r (f32 epilogue).
// LDS tiles bf16 [64][128], XOR-swizzled (byte ^= (row&7)<<4).
// MFMA C/D: col = l&15, row = (l>>4)*4 + reg  [verified mapping].
// ---------------------------------------------------------------------------
__global__ __launch_bounds__(256) void k_h_el_er(
    const float* __restrict__ x, const unsigned short* __restrict__ Wt,
    const float* __restrict__ a_l, const float* __restrict__ a_r,
    unsigned short* __restrict__ h_bf,
    float* __restrict__ el, float* __restrict__ er)
{
    __shared__ unsigned short xs[64 * 128];   // 16 KB, swizzled
    __shared__ unsigned short wsh[64 * 128];  // 16 KB, swizzled
    const int tid = threadIdx.x;
    const int node0 = blockIdx.x * 64;

    {
        const uint4* src = (const uint4*)Wt;
        #pragma unroll
        for (int j = 0; j < 4; ++j) {
            int idx = tid + 256 * j;
            int r = idx >> 4;
            int cb = (idx & 15) << 4;
            uint4 v = src[idx];
            *(uint4*)((char*)wsh + r * 256 + (cb ^ ((r & 7) << 4))) = v;
        }
    }
    {
        const int r = tid >> 2;
        const int c0 = (tid & 3) * 32;
        const int node = node0 + r;
        unsigned int pk[16];
        if (node < N_NODES) {
            const float* src = x + (size_t)node * IN_F + c0;
            #pragma unroll
            for (int i = 0; i < 8; ++i) {
                float4 v = *(const float4*)(src + 4 * i);
                pk[2 * i + 0] = (unsigned)f2bf(v.x) | ((unsigned)f2bf(v.y) << 16);
                pk[2 * i + 1] = (unsigned)f2bf(v.z) | ((unsigned)f2bf(v.w) << 16);
            }
        } else {
            #pragma unroll
            for (int i = 0; i < 16; ++i) pk[i] = 0;
        }
        #pragma unroll
        for (int q = 0; q < 4; ++q) {
            int cb = c0 * 2 + q * 16;
            *(uint4*)((char*)xs + r * 256 + (cb ^ ((r & 7) << 4))) =
                make_uint4(pk[4 * q], pk[4 * q + 1], pk[4 * q + 2], pk[4 * q + 3]);
        }
    }
    __syncthreads();

    const int w  = tid >> 6, l = tid & 63;
    const int lr = l & 15, lg = l >> 4;
    const int arow = w * 16 + lr;

    bf16x8 afr[4];
    #pragma unroll
    for (int t = 0; t < 4; ++t) {
        int cb = t * 64 + lg * 16;
        afr[t] = *(const bf16x8*)((char*)xs + arow * 256 + (cb ^ ((arow & 7) << 4)));
    }

    const f32x4 zero = {0.f, 0.f, 0.f, 0.f};
    f32x4 acc[4] = {zero, zero, zero, zero};
    #pragma unroll
    for (int nt = 0; nt < 4; ++nt) {
        const int brow = nt * 16 + lr;
        #pragma unroll
        for (int t = 0; t < 4; ++t) {
            int cb = t * 64 + lg * 16;
            bf16x8 bfr = *(const bf16x8*)((char*)wsh + brow * 256 + (cb ^ ((brow & 7) << 4)));
            acc[nt] = __builtin_amdgcn_mfma_f32_16x16x32_bf16(afr[t], bfr, acc[nt], 0, 0, 0);
        }
    }

    #pragma unroll
    for (int r = 0; r < 4; ++r) {
        const int node = node0 + w * 16 + lg * 4 + r;
        if (node < N_NODES) {
            #pragma unroll
            for (int nt = 0; nt < 4; ++nt)
                h_bf[(size_t)node * OUT_F + nt * 16 + lr] = f2bf(acc[nt][r]);
        }
    }

    float4 al4[4], ar4[4];
    #pragma unroll
    for (int nt = 0; nt < 4; ++nt) {
        al4[nt] = *(const float4*)(a_l + (size_t)(nt * 16 + lr) * N_HEADS);
        ar4[nt] = *(const float4*)(a_r + (size_t)(nt * 16 + lr) * N_HEADS);
    }
    #pragma unroll
    for (int r = 0; r < 4; ++r) {
        float4 pl = make_float4(0.f, 0.f, 0.f, 0.f);
        float4 pr = make_float4(0.f, 0.f, 0.f, 0.f);
        #pragma unroll
        for (int nt = 0; nt < 4; ++nt) {
            const float v = acc[nt][r];
            pl.x += v * al4[nt].x; pl.y += v * al4[nt].y;
            pl.z += v * al4[nt].z; pl.w += v * al4[nt].w;
            pr.x += v * ar4[nt].x; pr.y += v * ar4[nt].y;
            pr.z += v * ar4[nt].z; pr.w += v * ar4[nt].w;
        }
        #pragma unroll
        for (int off = 1; off < 16; off <<= 1) {
            pl.x += __shfl_xor(pl.x, off); pl.y += __shfl_xor(pl.y, off);
            pl.z += __shfl_xor(pl.z, off); pl.w += __shfl_xor(pl.w, off);
            pr.x += __shfl_xor(pr.x, off); pr.y += __shfl_xor(pr.y, off);
            pr.z += __shfl_xor(pr.z, off); pr.w += __shfl_xor(pr.w, off);
        }
        const int node = node0 + w * 16 + lg * 4 + r;
        if (lr == 0 && node < N_NODES) {
            *(float4*)(el + (size_t)node * N_HEADS) = pl;
            *(float4*)(er + (size_t)node * N_HEADS) = pr;
        }
    }
}

// ---------------------------------------------------------------------------
// S2a: per-block exclusive scan (1024 elems/block) of histG -> scanHist
// ---------------------------------------------------------------------------
__global__ __launch_bounds__(256) void k_scan2_local(
    const int* __restrict__ histG, int* __restrict__ scanHist,
    int* __restrict__ blocksum)
{
    __shared__ int wsum[4];
    const int t = threadIdx.x;
    const int base = blockIdx.x * 1024 + t * 4;

    int4 d = make_int4(0, 0, 0, 0);
    if (base + 3 < S2N) d = *(const int4*)(histG + base);
    else {
        if (base + 0 < S2N) d.x = histG[base + 0];
        if (base + 1 < S2N) d.y = histG[base + 1];
        if (base + 2 < S2N) d.z = histG[base + 2];
        if (base + 3 < S2N) d.w = histG[base + 3];
    }
    const int tsum = d.x + d.y + d.z + d.w;

    const int lane = t & 63, wave = t >> 6;
    int inc = tsum;
    #pragma unroll
    for (int off = 1; off < 64; off <<= 1) {
        int v = __shfl_up(inc, off);
        if (lane >= off) inc += v;
    }
    if (lane == 63) wsum[wave] = inc;
    __syncthreads();

    int woff = 0;
    #pragma unroll
    for (int w = 0; w < 4; ++w) woff += (w < wave) ? wsum[w] : 0;

    const int ex = woff + inc - tsum;
    int4 o;
    o.x = ex; o.y = ex + d.x; o.z = o.y + d.y; o.w = o.z + d.z;
    if (base + 3 < S2N) *(int4*)(scanHist + base) = o;
    else {
        if (base + 0 < S2N) scanHist[base + 0] = o.x;
        if (base + 1 < S2N) scanHist[base + 1] = o.y;
        if (base + 2 < S2N) scanHist[base + 2] = o.z;
        if (base + 3 < S2N) scanHist[base + 3] = o.w;
    }
    if (t == 0) blocksum[blockIdx.x] = wsum[0] + wsum[1] + wsum[2] + wsum[3];
}

// ---------------------------------------------------------------------------
// S2b: add preceding-block offsets into scanHist
// ---------------------------------------------------------------------------
__global__ __launch_bounds__(256) void k_scan2_add(
    const int* __restrict__ blocksum, int* __restrict__ scanHist)
{
    const int bb = blockIdx.x;
    int off = 0;
    for (int i = 0; i < bb; ++i) off += blocksum[i];
    if (off == 0) return;

    const int t = threadIdx.x;
    const int base = bb * 1024 + t * 4;
    if (base + 3 < S2N) {
        int4 v = *(int4*)(scanHist + base);
        v.x += off; v.y += off; v.z += off; v.w += off;
        *(int4*)(scanHist + base) = v;
    } else {
        if (base + 0 < S2N) scanHist[base + 0] += off;
        if (base + 1 < S2N) scanHist[base + 1] += off;
        if (base + 2 < S2N) scanHist[base + 2] += off;
        if (base + 3 < S2N) scanHist[base + 3] += off;
    }
}

// ---------------------------------------------------------------------------
// S3: bucket-scatter edges. Per chunk: LDS write cursors from scanHist,
// LDS-atomic slot allocation, store packed (row&127)<<17 | col.
// ---------------------------------------------------------------------------
__global__ __launch_bounds__(256) void k_scatter(
    const int* __restrict__ row, const int* __restrict__ col,
    const int* __restrict__ scanHist, unsigned* __restrict__ ebuf)
{
    __shared__ int off[NB];
    const int ch = blockIdx.x;
    const int t = threadIdx.x;
    for (int i = t; i < NB; i += 256) off[i] = scanHist[i * NCH + ch];
    __syncthreads();
    const int e0 = ch * CHUNK;
    #pragma unroll
    for (int k = 0; k < 16; ++k) {
        const int e = e0 + t + k * 256;
        if (e < N_EDGES) {
            const int r = row[e], c = col[e];
            const int pos = atomicAdd(&off[r >> 7], 1);
            ebuf[pos] = ((unsigned)(r & 127) << 17) | (unsigned)c;
        }
    }
}

// ---------------------------------------------------------------------------
// S4: per-bucket CSR finalize. Count 128 local rows (LDS), scan, write
// rowptr; then scatter packed edge records {col, w01(bf16), w23(bf16), 0}
// into the bucket-local region (single block -> single XCD).
// ---------------------------------------------------------------------------
__global__ __launch_bounds__(256) void k_bucket(
    const unsigned* __restrict__ ebuf, const int* __restrict__ scanHist,
    const float* __restrict__ el, const float* __restrict__ er,
    int* __restrict__ rowptr, uint4* __restrict__ edata)
{
    __shared__ float4 elv[128];
    __shared__ int cnt[128];
    __shared__ int wsum2[2];
    const int b = blockIdx.x;
    const int t = threadIdx.x;
    const int node0 = b << 7;
    const int base = scanHist[b * NCH];
    const int end  = (b < NB - 1) ? scanHist[(b + 1) * NCH] : N_EDGES;

    if (t < 128) {
        const int node = node0 + t;
        elv[t] = (node < N_NODES) ? *(const float4*)(el + node * 4)
                                  : make_float4(0.f, 0.f, 0.f, 0.f);
        cnt[t] = 0;
    }
    __syncthreads();
    for (int i = base + t; i < end; i += 256)
        atomicAdd(&cnt[ebuf[i] >> 17], 1);
    __syncthreads();

    int inc = 0, val = 0;
    const int lane = t & 63, wave = t >> 6;
    if (t < 128) {
        val = cnt[t];
        inc = val;
        #pragma unroll
        for (int off = 1; off < 64; off <<= 1) {
            int v = __shfl_up(inc, off);
            if (lane >= off) inc += v;
        }
        if (lane == 63) wsum2[wave] = inc;
    }
    __syncthreads();
    int excl = 0;
    if (t < 128) {
        const int woff = (wave == 1) ? wsum2[0] : 0;
        excl = base + woff + inc - val;
        const int node = node0 + t;
        if (node < N_NODES) rowptr[node] = excl;
    }
    if (b == NB - 1 && t == 0) rowptr[N_NODES] = N_EDGES;
    __syncthreads();
    if (t < 128) cnt[t] = excl;   // reuse as write cursors
    __syncthreads();

    for (int i = base + t; i < end; i += 256) {
        const unsigned p = ebuf[i];
        const int r = p >> 17;
        const int c = (int)(p & 0x1FFFFu);
        const int pos = atomicAdd(&cnt[r], 1);
        const float4 e4 = elv[r];
        const float4 r4 = *(const float4*)(er + ((unsigned)c << 2));
        float s0 = e4.x + r4.x, s1 = e4.y + r4.y;
        float s2 = e4.z + r4.z, s3 = e4.w + r4.w;
        s0 = s0 > 0.f ? s0 : NEG_SLOPE * s0;
        s1 = s1 > 0.f ? s1 : NEG_SLOPE * s1;
        s2 = s2 > 0.f ? s2 : NEG_SLOPE * s2;
        s3 = s3 > 0.f ? s3 : NEG_SLOPE * s3;
        const unsigned w01 = (unsigned)f2bf(__expf(s0)) | ((unsigned)f2bf(__expf(s1)) << 16);
        const unsigned w23 = (unsigned)f2bf(__expf(s2)) | ((unsigned)f2bf(__expf(s3)) << 16);
        edata[pos] = make_uint4((unsigned)c, w01, w23, 0u);
    }
}

// ---------------------------------------------------------------------------
// K5: gather — one wave per node; 4 x 16-lane groups, 2 edges per group per
// iteration (8/wave-iter), 1-ahead pipeline, branch-free clamped loads.
// Edge record: uint4 {col, w01 bf16x2, w23 bf16x2, 0}.
// ---------------------------------------------------------------------------
__global__ __launch_bounds__(256) void k_gather(
    const int* __restrict__ rowptr, const uint4* __restrict__ edata,
    const unsigned short* __restrict__ h_bf, const float* __restrict__ b,
    float* __restrict__ out)
{
    int n = blockIdx.x * 4 + (threadIdx.x >> 6);
    if (n >= N_NODES) return;
    const int lane = threadIdx.x & 63;
    const int g    = lane >> 4;    // group == output head at the end
    const int fq   = lane & 15;    // feature quad: feats fq*4 .. +3

    const int s0 = rowptr[n], s1 = rowptr[n + 1];
    const int nit = (s1 - s0 + 7) >> 3;

    float acc[4][4];
    #pragma unroll
    for (int hd = 0; hd < 4; ++hd)
        #pragma unroll
        for (int f = 0; f < 4; ++f) acc[hd][f] = 0.f;
    float den[4] = {0.f, 0.f, 0.f, 0.f};

    if (nit > 0) {   // s1 > s0 guaranteed inside
#define LOADE(ii, E0, E1)                                   \
        {                                                   \
            const int j0 = s0 + (ii) * 8 + 2 * g;           \
            const int j1 = j0 + 1;                          \
            E0 = edata[j0 < s1 ? j0 : s1 - 1];              \
            E1 = edata[j1 < s1 ? j1 : s1 - 1];              \
            if (j0 >= s1) { E0.y = 0u; E0.z = 0u; }         \
            if (j1 >= s1) { E1.y = 0u; E1.z = 0u; }         \
        }
#define LOADH(E, H)                                                              \
        H = *(const uint2*)(h_bf + (((E.x & 0xFFFFu) << 6) + ((unsigned)fq << 2)));
#define COMP1(E, H)                                                              \
        {                                                                        \
            const float w0 = bf_lo(E.y), w1 = bf_hi(E.y);                        \
            const float w2 = bf_lo(E.z), w3 = bf_hi(E.z);                        \
            const float f0 = bf_lo(H.x), f1 = bf_hi(H.x);                        \
            const float f2 = bf_lo(H.y), f3 = bf_hi(H.y);                        \
            den[0] += w0; den[1] += w1; den[2] += w2; den[3] += w3;              \
            acc[0][0] += w0 * f0; acc[0][1] += w0 * f1;                          \
            acc[0][2] += w0 * f2; acc[0][3] += w0 * f3;                          \
            acc[1][0] += w1 * f0; acc[1][1] += w1 * f1;                          \
            acc[1][2] += w1 * f2; acc[1][3] += w1 * f3;                          \
            acc[2][0] += w2 * f0; acc[2][1] += w2 * f1;                          \
            acc[2][2] += w2 * f2; acc[2][3] += w2 * f3;                          \
            acc[3][0] += w3 * f0; acc[3][1] += w3 * f1;                          \
            acc[3][2] += w3 * f2; acc[3][3] += w3 * f3;                          \
        }

        uint4 a0, a1, b0, b1;
        uint2 ha0, ha1, hb0, hb1;
        LOADE(0, a0, a1);
        LOADH(a0, ha0); LOADH(a1, ha1);

        for (int it = 0; it < nit; ++it) {
            LOADE(it + 1, b0, b1);
            LOADH(b0, hb0); LOADH(b1, hb1);
            COMP1(a0, ha0);
            COMP1(a1, ha1);
            a0 = b0; a1 = b1; ha0 = hb0; ha1 = hb1;
        }
#undef LOADE
#undef LOADH
#undef COMP1
    }

    // reduce partials across the 4 groups (lanes xor 16, 32)
    #pragma unroll
    for (int hd = 0; hd < 4; ++hd) {
        float v = den[hd];
        v += __shfl_xor(v, 16); v += __shfl_xor(v, 32);
        den[hd] = v;
        #pragma unroll
        for (int f = 0; f < 4; ++f) {
            float u = acc[hd][f];
            u += __shfl_xor(u, 16); u += __shfl_xor(u, 32);
            acc[hd][f] = u;
        }
    }

    const float dg = g == 0 ? den[0] : g == 1 ? den[1] : g == 2 ? den[2] : den[3];
    const float inv = 1.f / fmaxf(dg, EPS);
    float4 o;
    o.x = (g == 0 ? acc[0][0] : g == 1 ? acc[1][0] : g == 2 ? acc[2][0] : acc[3][0]);
    o.y = (g == 0 ? acc[0][1] : g == 1 ? acc[1][1] : g == 2 ? acc[2][1] : acc[3][1]);
    o.z = (g == 0 ? acc[0][2] : g == 1 ? acc[1][2] : g == 2 ? acc[2][2] : acc[3][2]);
    o.w = (g == 0 ? acc[0][3] : g == 1 ? acc[1][3] : g == 2 ? acc[2][3] : acc[3][3]);

    const float4 bias = *(const float4*)(b + fq * 4);
    o.x = o.x * inv + bias.x;
    o.y = o.y * inv + bias.y;
    o.z = o.z * inv + bias.z;
    o.w = o.w * inv + bias.w;
    *(float4*)(out + (size_t)n * (N_HEADS * OUT_F) + g * 64 + fq * 4) = o;
}

extern "C" void kernel_launch(void* const* d_in, const int* in_sizes, int n_in,
                              void* d_out, int out_size, void* d_ws, size_t ws_size,
                              hipStream_t stream)
{
    const float* x   = (const float*)d_in[0];
    const int*   ei  = (const int*)d_in[1];
    const float* W   = (const float*)d_in[2];
    const float* a_l = (const float*)d_in[3];
    const float* a_r = (const float*)d_in[4];
    const float* b   = (const float*)d_in[5];
    float* out = (float*)d_out;

    char* ws = (char*)d_ws;
    unsigned short* h_bf = (unsigned short*)(ws);          //  6,400,000 B
    float*    el       = (float*)   (ws +  6400000);       //    800,000 B
    float*    er       = (float*)   (ws +  7200000);       //    800,000 B
    unsigned short* Wt = (unsigned short*)(ws + 8000000);  //     16,384 B
    int*      histG    = (int*)     (ws +  8016384);       //    306,544 B
    int*      scanHist = (int*)     (ws +  8322928);       //    306,544 B
    int*      blocksum = (int*)     (ws +  8629472);       //      1,024 B
    unsigned* ebuf     = (unsigned*)(ws +  8630496);       //  3,200,000 B
    int*      rowptr   = (int*)     (ws + 11830496);       //    200,016 B
    uint4*    edata    = (uint4*)   (ws + 12030512);       // 12,800,016 B (+1 pad)
    // total: 24,830,528 B

    const int* row = ei;
    const int* col = ei + N_EDGES;

    k_init       <<<4 + NCH, 256, 0, stream>>>(W, Wt, row, histG);
    k_h_el_er    <<<NODE_BLOCKS, 256, 0, stream>>>(x, Wt, a_l, a_r, h_bf, el, er);
    k_scan2_local<<<S2B, 256, 0, stream>>>(histG, scanHist, blocksum);
    k_scan2_add  <<<S2B, 256, 0, stream>>>(blocksum, scanHist);
    k_scatter    <<<NCH, 256, 0, stream>>>(row, col, scanHist, ebuf);
    k_bucket     <<<NB, 256, 0, stream>>>(ebuf, scanHist, el, er, rowptr, edata);
    k_gather     <<<N_NODES / 4, 256, 0, stream>>>(rowptr, edata, h_bf, b, out);
}

// Round 13
// 79.866 us; speedup vs baseline: 3.9069x; 1.0703x over previous
//
#include <hip/hip_runtime.h>

#define N_NODES 50000
#define N_EDGES 800000
#define IN_F    128
#define OUT_F   64
#define N_HEADS 4
#define NEG_SLOPE 0.2f
#define EPS 1e-12f

#define NODE_BLOCKS 782   // ceil(50000 / 64) for the MFMA part
#define NB    391         // buckets of 128 rows: bucket = row >> 7
#define CHUNK 4096        // edges per histogram/scatter chunk
#define NCH   196         // 196*4096 = 802816 >= 800000
#define S2N   (NB * NCH)  // 76636 histogram entries
#define S2B   75          // scan blocks: 75*1024 = 76800 >= S2N

typedef __attribute__((ext_vector_type(8))) short bf16x8;
typedef __attribute__((ext_vector_type(4))) float f32x4;

// bf16 helpers (RNE)
__device__ __forceinline__ unsigned short f2bf(float f) {
    unsigned int u = __float_as_uint(f);
    u += 0x7FFFu + ((u >> 16) & 1u);
    return (unsigned short)(u >> 16);
}
__device__ __forceinline__ float bf_lo(unsigned u) { return __uint_as_float(u << 16); }
__device__ __forceinline__ float bf_hi(unsigned u) { return __uint_as_float(u & 0xFFFF0000u); }

// ---------------------------------------------------------------------------
// K1 fused: blocks [0, NCH): per-chunk bucket histogram (LDS atomics);
// blocks [NCH, NCH+NODE_BLOCKS): h = x@W via MFMA bf16 with fused el/er
// epilogue. W converted f32->bf16 in-block (no prep pass).
// LDS tiles bf16 [64][128], XOR-swizzled (byte ^= (row&7)<<4).
// MFMA C/D: col = l&15, row = (l>>4)*4 + reg  [verified mapping].
// ---------------------------------------------------------------------------
__global__ __launch_bounds__(256) void k_hist_gemm(
    const float* __restrict__ x, const float* __restrict__ W,
    const float* __restrict__ a_l, const float* __restrict__ a_r,
    const int* __restrict__ row, int* __restrict__ histG,
    unsigned short* __restrict__ h_bf,
    float* __restrict__ el, float* __restrict__ er)
{
    __shared__ int hist[NB];
    __shared__ unsigned short xs[64 * 128];   // 16 KB, swizzled
    __shared__ unsigned short wsh[64 * 128];  // 16 KB, swizzled
    const int tid = threadIdx.x;

    if (blockIdx.x < NCH) {
        // ---- histogram part ----
        const int ch = blockIdx.x;
        for (int i = tid; i < NB; i += 256) hist[i] = 0;
        __syncthreads();
        const int e0 = ch * CHUNK + tid * 16;
        #pragma unroll
        for (int q = 0; q < 4; ++q) {
            const int e = e0 + q * 4;
            if (e + 3 < N_EDGES) {
                int4 a = *(const int4*)(row + e);
                atomicAdd(&hist[a.x >> 7], 1); atomicAdd(&hist[a.y >> 7], 1);
                atomicAdd(&hist[a.z >> 7], 1); atomicAdd(&hist[a.w >> 7], 1);
            } else {
                #pragma unroll
                for (int j = 0; j < 4; ++j)
                    if (e + j < N_EDGES) atomicAdd(&hist[row[e + j] >> 7], 1);
            }
        }
        __syncthreads();
        for (int i = tid; i < NB; i += 256) histG[i * NCH + ch] = hist[i];
        return;
    }

    // ---- GEMM part ----
    const int node0 = (blockIdx.x - NCH) * 64;

    {   // stage W transposed+bf16+swizzled: thread t: col c = t&63, kq = t>>6
        const int c  = tid & 63;
        const int kq = tid >> 6;          // k-range kq*32 .. +31
        #pragma unroll
        for (int kb = 0; kb < 32; kb += 8) {
            unsigned pk[4];
            #pragma unroll
            for (int i = 0; i < 4; ++i) {
                const int k = kq * 32 + kb + 2 * i;
                const float v0 = W[k * OUT_F + c];        // wave-coalesced 256B
                const float v1 = W[(k + 1) * OUT_F + c];
                pk[i] = (unsigned)f2bf(v0) | ((unsigned)f2bf(v1) << 16);
            }
            const int cb = (kq * 32 + kb) * 2;            // byte col offset
            *(uint4*)((char*)wsh + c * 256 + (cb ^ ((c & 7) << 4))) =
                make_uint4(pk[0], pk[1], pk[2], pk[3]);
        }
    }
    {   // stage x rows (f32 -> bf16)
        const int r = tid >> 2;
        const int c0 = (tid & 3) * 32;
        const int node = node0 + r;
        unsigned int pk[16];
        if (node < N_NODES) {
            const float* src = x + (size_t)node * IN_F + c0;
            #pragma unroll
            for (int i = 0; i < 8; ++i) {
                float4 v = *(const float4*)(src + 4 * i);
                pk[2 * i + 0] = (unsigned)f2bf(v.x) | ((unsigned)f2bf(v.y) << 16);
                pk[2 * i + 1] = (unsigned)f2bf(v.z) | ((unsigned)f2bf(v.w) << 16);
            }
        } else {
            #pragma unroll
            for (int i = 0; i < 16; ++i) pk[i] = 0;
        }
        #pragma unroll
        for (int q = 0; q < 4; ++q) {
            int cb = c0 * 2 + q * 16;
            *(uint4*)((char*)xs + r * 256 + (cb ^ ((r & 7) << 4))) =
                make_uint4(pk[4 * q], pk[4 * q + 1], pk[4 * q + 2], pk[4 * q + 3]);
        }
    }
    __syncthreads();

    const int w  = tid >> 6, l = tid & 63;
    const int lr = l & 15, lg = l >> 4;
    const int arow = w * 16 + lr;

    bf16x8 afr[4];
    #pragma unroll
    for (int t = 0; t < 4; ++t) {
        int cb = t * 64 + lg * 16;
        afr[t] = *(const bf16x8*)((char*)xs + arow * 256 + (cb ^ ((arow & 7) << 4)));
    }

    const f32x4 zero = {0.f, 0.f, 0.f, 0.f};
    f32x4 acc[4] = {zero, zero, zero, zero};
    #pragma unroll
    for (int nt = 0; nt < 4; ++nt) {
        const int brow = nt * 16 + lr;
        #pragma unroll
        for (int t = 0; t < 4; ++t) {
            int cb = t * 64 + lg * 16;
            bf16x8 bfr = *(const bf16x8*)((char*)wsh + brow * 256 + (cb ^ ((brow & 7) << 4)));
            acc[nt] = __builtin_amdgcn_mfma_f32_16x16x32_bf16(afr[t], bfr, acc[nt], 0, 0, 0);
        }
    }

    #pragma unroll
    for (int r = 0; r < 4; ++r) {
        const int node = node0 + w * 16 + lg * 4 + r;
        if (node < N_NODES) {
            #pragma unroll
            for (int nt = 0; nt < 4; ++nt)
                h_bf[(size_t)node * OUT_F + nt * 16 + lr] = f2bf(acc[nt][r]);
        }
    }

    float4 al4[4], ar4[4];
    #pragma unroll
    for (int nt = 0; nt < 4; ++nt) {
        al4[nt] = *(const float4*)(a_l + (size_t)(nt * 16 + lr) * N_HEADS);
        ar4[nt] = *(const float4*)(a_r + (size_t)(nt * 16 + lr) * N_HEADS);
    }
    #pragma unroll
    for (int r = 0; r < 4; ++r) {
        float4 pl = make_float4(0.f, 0.f, 0.f, 0.f);
        float4 pr = make_float4(0.f, 0.f, 0.f, 0.f);
        #pragma unroll
        for (int nt = 0; nt < 4; ++nt) {
            const float v = acc[nt][r];
            pl.x += v * al4[nt].x; pl.y += v * al4[nt].y;
            pl.z += v * al4[nt].z; pl.w += v * al4[nt].w;
            pr.x += v * ar4[nt].x; pr.y += v * ar4[nt].y;
            pr.z += v * ar4[nt].z; pr.w += v * ar4[nt].w;
        }
        #pragma unroll
        for (int off = 1; off < 16; off <<= 1) {
            pl.x += __shfl_xor(pl.x, off); pl.y += __shfl_xor(pl.y, off);
            pl.z += __shfl_xor(pl.z, off); pl.w += __shfl_xor(pl.w, off);
            pr.x += __shfl_xor(pr.x, off); pr.y += __shfl_xor(pr.y, off);
            pr.z += __shfl_xor(pr.z, off); pr.w += __shfl_xor(pr.w, off);
        }
        const int node = node0 + w * 16 + lg * 4 + r;
        if (lr == 0 && node < N_NODES) {
            *(float4*)(el + (size_t)node * N_HEADS) = pl;
            *(float4*)(er + (size_t)node * N_HEADS) = pr;
        }
    }
}

// ---------------------------------------------------------------------------
// S2a: per-block exclusive scan (1024 elems/block) of histG -> scanHist
// ---------------------------------------------------------------------------
__global__ __launch_bounds__(256) void k_scan2_local(
    const int* __restrict__ histG, int* __restrict__ scanHist,
    int* __restrict__ blocksum)
{
    __shared__ int wsum[4];
    const int t = threadIdx.x;
    const int base = blockIdx.x * 1024 + t * 4;

    int4 d = make_int4(0, 0, 0, 0);
    if (base + 3 < S2N) d = *(const int4*)(histG + base);
    else {
        if (base + 0 < S2N) d.x = histG[base + 0];
        if (base + 1 < S2N) d.y = histG[base + 1];
        if (base + 2 < S2N) d.z = histG[base + 2];
        if (base + 3 < S2N) d.w = histG[base + 3];
    }
    const int tsum = d.x + d.y + d.z + d.w;

    const int lane = t & 63, wave = t >> 6;
    int inc = tsum;
    #pragma unroll
    for (int off = 1; off < 64; off <<= 1) {
        int v = __shfl_up(inc, off);
        if (lane >= off) inc += v;
    }
    if (lane == 63) wsum[wave] = inc;
    __syncthreads();

    int woff = 0;
    #pragma unroll
    for (int w = 0; w < 4; ++w) woff += (w < wave) ? wsum[w] : 0;

    const int ex = woff + inc - tsum;
    int4 o;
    o.x = ex; o.y = ex + d.x; o.z = o.y + d.y; o.w = o.z + d.z;
    if (base + 3 < S2N) *(int4*)(scanHist + base) = o;
    else {
        if (base + 0 < S2N) scanHist[base + 0] = o.x;
        if (base + 1 < S2N) scanHist[base + 1] = o.y;
        if (base + 2 < S2N) scanHist[base + 2] = o.z;
        if (base + 3 < S2N) scanHist[base + 3] = o.w;
    }
    if (t == 0) blocksum[blockIdx.x] = wsum[0] + wsum[1] + wsum[2] + wsum[3];
}

// ---------------------------------------------------------------------------
// S2b: add preceding-block offsets into scanHist
// ---------------------------------------------------------------------------
__global__ __launch_bounds__(256) void k_scan2_add(
    const int* __restrict__ blocksum, int* __restrict__ scanHist)
{
    const int bb = blockIdx.x;
    int off = 0;
    for (int i = 0; i < bb; ++i) off += blocksum[i];
    if (off == 0) return;

    const int t = threadIdx.x;
    const int base = bb * 1024 + t * 4;
    if (base + 3 < S2N) {
        int4 v = *(int4*)(scanHist + base);
        v.x += off; v.y += off; v.z += off; v.w += off;
        *(int4*)(scanHist + base) = v;
    } else {
        if (base + 0 < S2N) scanHist[base + 0] += off;
        if (base + 1 < S2N) scanHist[base + 1] += off;
        if (base + 2 < S2N) scanHist[base + 2] += off;
        if (base + 3 < S2N) scanHist[base + 3] += off;
    }
}

// ---------------------------------------------------------------------------
// S3: bucket-scatter edges. Per chunk: LDS write cursors from scanHist,
// LDS-atomic slot allocation, store packed (row&127)<<17 | col.
// ---------------------------------------------------------------------------
__global__ __launch_bounds__(256) void k_scatter(
    const int* __restrict__ row, const int* __restrict__ col,
    const int* __restrict__ scanHist, unsigned* __restrict__ ebuf)
{
    __shared__ int off[NB];
    const int ch = blockIdx.x;
    const int t = threadIdx.x;
    for (int i = t; i < NB; i += 256) off[i] = scanHist[i * NCH + ch];
    __syncthreads();
    const int e0 = ch * CHUNK;
    #pragma unroll
    for (int k = 0; k < 16; ++k) {
        const int e = e0 + t + k * 256;
        if (e < N_EDGES) {
            const int r = row[e], c = col[e];
            const int pos = atomicAdd(&off[r >> 7], 1);
            ebuf[pos] = ((unsigned)(r & 127) << 17) | (unsigned)c;
        }
    }
}

// ---------------------------------------------------------------------------
// S4: per-bucket CSR finalize. Count 128 local rows (LDS), scan, write
// rowptr; then scatter packed edge records {col, w01(bf16), w23(bf16), 0}
// into the bucket-local region (single block -> single XCD).
// ---------------------------------------------------------------------------
__global__ __launch_bounds__(256) void k_bucket(
    const unsigned* __restrict__ ebuf, const int* __restrict__ scanHist,
    const float* __restrict__ el, const float* __restrict__ er,
    int* __restrict__ rowptr, uint4* __restrict__ edata)
{
    __shared__ float4 elv[128];
    __shared__ int cnt[128];
    __shared__ int wsum2[2];
    const int b = blockIdx.x;
    const int t = threadIdx.x;
    const int node0 = b << 7;
    const int base = scanHist[b * NCH];
    const int end  = (b < NB - 1) ? scanHist[(b + 1) * NCH] : N_EDGES;

    if (t < 128) {
        const int node = node0 + t;
        elv[t] = (node < N_NODES) ? *(const float4*)(el + node * 4)
                                  : make_float4(0.f, 0.f, 0.f, 0.f);
        cnt[t] = 0;
    }
    __syncthreads();
    for (int i = base + t; i < end; i += 256)
        atomicAdd(&cnt[ebuf[i] >> 17], 1);
    __syncthreads();

    int inc = 0, val = 0;
    const int lane = t & 63, wave = t >> 6;
    if (t < 128) {
        val = cnt[t];
        inc = val;
        #pragma unroll
        for (int off = 1; off < 64; off <<= 1) {
            int v = __shfl_up(inc, off);
            if (lane >= off) inc += v;
        }
        if (lane == 63) wsum2[wave] = inc;
    }
    __syncthreads();
    int excl = 0;
    if (t < 128) {
        const int woff = (wave == 1) ? wsum2[0] : 0;
        excl = base + woff + inc - val;
        const int node = node0 + t;
        if (node < N_NODES) rowptr[node] = excl;
    }
    if (b == NB - 1 && t == 0) rowptr[N_NODES] = N_EDGES;
    __syncthreads();
    if (t < 128) cnt[t] = excl;   // reuse as write cursors
    __syncthreads();

    for (int i = base + t; i < end; i += 256) {
        const unsigned p = ebuf[i];
        const int r = p >> 17;
        const int c = (int)(p & 0x1FFFFu);
        const int pos = atomicAdd(&cnt[r], 1);
        const float4 e4 = elv[r];
        const float4 r4 = *(const float4*)(er + ((unsigned)c << 2));
        float s0 = e4.x + r4.x, s1 = e4.y + r4.y;
        float s2 = e4.z + r4.z, s3 = e4.w + r4.w;
        s0 = s0 > 0.f ? s0 : NEG_SLOPE * s0;
        s1 = s1 > 0.f ? s1 : NEG_SLOPE * s1;
        s2 = s2 > 0.f ? s2 : NEG_SLOPE * s2;
        s3 = s3 > 0.f ? s3 : NEG_SLOPE * s3;
        const unsigned w01 = (unsigned)f2bf(__expf(s0)) | ((unsigned)f2bf(__expf(s1)) << 16);
        const unsigned w23 = (unsigned)f2bf(__expf(s2)) | ((unsigned)f2bf(__expf(s3)) << 16);
        edata[pos] = make_uint4((unsigned)c, w01, w23, 0u);
    }
}

// ---------------------------------------------------------------------------
// K5: gather — one wave per node; 4 x 16-lane groups, 2 edges per group per
// iteration (8/wave-iter), 1-ahead pipeline, branch-free clamped loads.
// Edge record: uint4 {col, w01 bf16x2, w23 bf16x2, 0}.
// ---------------------------------------------------------------------------
__global__ __launch_bounds__(256) void k_gather(
    const int* __restrict__ rowptr, const uint4* __restrict__ edata,
    const unsigned short* __restrict__ h_bf, const float* __restrict__ b,
    float* __restrict__ out)
{
    int n = blockIdx.x * 4 + (threadIdx.x >> 6);
    if (n >= N_NODES) return;
    const int lane = threadIdx.x & 63;
    const int g    = lane >> 4;    // group == output head at the end
    const int fq   = lane & 15;    // feature quad: feats fq*4 .. +3

    const int s0 = rowptr[n], s1 = rowptr[n + 1];
    const int nit = (s1 - s0 + 7) >> 3;

    float acc[4][4];
    #pragma unroll
    for (int hd = 0; hd < 4; ++hd)
        #pragma unroll
        for (int f = 0; f < 4; ++f) acc[hd][f] = 0.f;
    float den[4] = {0.f, 0.f, 0.f, 0.f};

    if (nit > 0) {   // s1 > s0 guaranteed inside
#define LOADE(ii, E0, E1)                                   \
        {                                                   \
            const int j0 = s0 + (ii) * 8 + 2 * g;           \
            const int j1 = j0 + 1;                          \
            E0 = edata[j0 < s1 ? j0 : s1 - 1];              \
            E1 = edata[j1 < s1 ? j1 : s1 - 1];              \
            if (j0 >= s1) { E0.y = 0u; E0.z = 0u; }         \
            if (j1 >= s1) { E1.y = 0u; E1.z = 0u; }         \
        }
#define LOADH(E, H)                                                              \
        H = *(const uint2*)(h_bf + (((E.x & 0xFFFFu) << 6) + ((unsigned)fq << 2)));
#define COMP1(E, H)                                                              \
        {                                                                        \
            const float w0 = bf_lo(E.y), w1 = bf_hi(E.y);                        \
            const float w2 = bf_lo(E.z), w3 = bf_hi(E.z);                        \
            const float f0 = bf_lo(H.x), f1 = bf_hi(H.x);                        \
            const float f2 = bf_lo(H.y), f3 = bf_hi(H.y);                        \
            den[0] += w0; den[1] += w1; den[2] += w2; den[3] += w3;              \
            acc[0][0] += w0 * f0; acc[0][1] += w0 * f1;                          \
            acc[0][2] += w0 * f2; acc[0][3] += w0 * f3;                          \
            acc[1][0] += w1 * f0; acc[1][1] += w1 * f1;                          \
            acc[1][2] += w1 * f2; acc[1][3] += w1 * f3;                          \
            acc[2][0] += w2 * f0; acc[2][1] += w2 * f1;                          \
            acc[2][2] += w2 * f2; acc[2][3] += w2 * f3;                          \
            acc[3][0] += w3 * f0; acc[3][1] += w3 * f1;                          \
            acc[3][2] += w3 * f2; acc[3][3] += w3 * f3;                          \
        }

        uint4 a0, a1, b0, b1;
        uint2 ha0, ha1, hb0, hb1;
        LOADE(0, a0, a1);
        LOADH(a0, ha0); LOADH(a1, ha1);

        for (int it = 0; it < nit; ++it) {
            LOADE(it + 1, b0, b1);
            LOADH(b0, hb0); LOADH(b1, hb1);
            COMP1(a0, ha0);
            COMP1(a1, ha1);
            a0 = b0; a1 = b1; ha0 = hb0; ha1 = hb1;
        }
#undef LOADE
#undef LOADH
#undef COMP1
    }

    // reduce partials across the 4 groups (lanes xor 16, 32)
    #pragma unroll
    for (int hd = 0; hd < 4; ++hd) {
        float v = den[hd];
        v += __shfl_xor(v, 16); v += __shfl_xor(v, 32);
        den[hd] = v;
        #pragma unroll
        for (int f = 0; f < 4; ++f) {
            float u = acc[hd][f];
            u += __shfl_xor(u, 16); u += __shfl_xor(u, 32);
            acc[hd][f] = u;
        }
    }

    const float dg = g == 0 ? den[0] : g == 1 ? den[1] : g == 2 ? den[2] : den[3];
    const float inv = 1.f / fmaxf(dg, EPS);
    float4 o;
    o.x = (g == 0 ? acc[0][0] : g == 1 ? acc[1][0] : g == 2 ? acc[2][0] : acc[3][0]);
    o.y = (g == 0 ? acc[0][1] : g == 1 ? acc[1][1] : g == 2 ? acc[2][1] : acc[3][1]);
    o.z = (g == 0 ? acc[0][2] : g == 1 ? acc[1][2] : g == 2 ? acc[2][2] : acc[3][2]);
    o.w = (g == 0 ? acc[0][3] : g == 1 ? acc[1][3] : g == 2 ? acc[2][3] : acc[3][3]);

    const float4 bias = *(const float4*)(b + fq * 4);
    o.x = o.x * inv + bias.x;
    o.y = o.y * inv + bias.y;
    o.z = o.z * inv + bias.z;
    o.w = o.w * inv + bias.w;
    *(float4*)(out + (size_t)n * (N_HEADS * OUT_F) + g * 64 + fq * 4) = o;
}

extern "C" void kernel_launch(void* const* d_in, const int* in_sizes, int n_in,
                              void* d_out, int out_size, void* d_ws, size_t ws_size,
                              hipStream_t stream)
{
    const float* x   = (const float*)d_in[0];
    const int*   ei  = (const int*)d_in[1];
    const float* W   = (const float*)d_in[2];
    const float* a_l = (const float*)d_in[3];
    const float* a_r = (const float*)d_in[4];
    const float* b   = (const float*)d_in[5];
    float* out = (float*)d_out;

    char* ws = (char*)d_ws;
    unsigned short* h_bf = (unsigned short*)(ws);          //  6,400,000 B
    float*    el       = (float*)   (ws +  6400000);       //    800,000 B
    float*    er       = (float*)   (ws +  7200000);       //    800,000 B
    int*      histG    = (int*)     (ws +  8000000);       //    306,544 B
    int*      scanHist = (int*)     (ws +  8306544);       //    306,544 B
    int*      blocksum = (int*)     (ws +  8613088);       //      1,024 B
    unsigned* ebuf     = (unsigned*)(ws +  8614112);       //  3,200,000 B
    int*      rowptr   = (int*)     (ws + 11814112);       //    200,016 B
    uint4*    edata    = (uint4*)   (ws + 12014128);       // 12,800,016 B
    // total: 24,814,144 B

    const int* row = ei;
    const int* col = ei + N_EDGES;

    k_hist_gemm  <<<NCH + NODE_BLOCKS, 256, 0, stream>>>(
                     x, W, a_l, a_r, row, histG, h_bf, el, er);
    k_scan2_local<<<S2B, 256, 0, stream>>>(histG, scanHist, blocksum);
    k_scan2_add  <<<S2B, 256, 0, stream>>>(blocksum, scanHist);
    k_scatter    <<<NCH, 256, 0, stream>>>(row, col, scanHist, ebuf);
    k_bucket     <<<NB, 256, 0, stream>>>(ebuf, scanHist, el, er, rowptr, edata);
    k_gather     <<<N_NODES / 4, 256, 0, stream>>>(rowptr, edata, h_bf, b, out);
}